// Round 9
// baseline (341.533 us; speedup 1.0000x reference)
//
#include <hip/hip_runtime.h>
#include <math.h>
#include <stdint.h>

#define NCLS   80
#define NPTS   8400
#define KEEP   100
#define PRETOPK 5000
#define NB     8
#define THRBITS 0x3C23D70Au   // bits of 0.01f (scores positive floats -> int-ordered)

#define CAPF   512            // candidate cap per class
#define NEEDF  192u           // selection target
#define NITER  132            // ceil(8400/64)

#define TBT    1024           // topk block size
#define NREGT  8              // 8000/1024
#define CAPT   512

__device__ __forceinline__ float sigmoidf_(float x) { return 1.0f / (1.0f + expf(-x)); }

__device__ __forceinline__ uint32_t score_key(int n, int b, int c,
        const float* cls0, const float* obj0, const float* cls1, const float* obj1,
        const float* cls2, const float* obj2) {
    const float *clsP, *objP; int base, HW;
    if (n < 6400)      { clsP = cls0; objP = obj0; base = n;        HW = 6400; }
    else if (n < 8000) { clsP = cls1; objP = obj1; base = n - 6400; HW = 1600; }
    else               { clsP = cls2; objP = obj2; base = n - 8000; HW = 400;  }
    float cv = clsP[((size_t)b * NCLS + c) * HW + base];
    float ov = objP[(size_t)b * HW + base];
    return __float_as_uint(sigmoidf_(cv) * sigmoidf_(ov));
}

__device__ __forceinline__ void level_of(int n, int& base, int& W, int& HW, float& s, int& lvl) {
    if (n < 6400)      { lvl = 0; base = n;        W = 80; HW = 6400; s = 8.f;  }
    else if (n < 8000) { lvl = 1; base = n - 6400; W = 40; HW = 1600; s = 16.f; }
    else               { lvl = 2; base = n - 8000; W = 20; HW = 400;  s = 32.f; }
}

// ---------------------------------------------------------------- decode boxes (R6-proven)
__global__ void decode_boxes(const float* __restrict__ bb0,
                             const float* __restrict__ bb1,
                             const float* __restrict__ bb2,
                             float4* __restrict__ boxes) {
    int t = blockIdx.x * blockDim.x + threadIdx.x;
    if (t >= NB * NPTS) return;
    int b = t / NPTS, n = t - b * NPTS;
    int base, W, HW, lvl; float s;
    level_of(n, base, W, HW, s, lvl);
    const float* bb = (lvl == 0) ? bb0 : ((lvl == 1) ? bb1 : bb2);
    const float* p = bb + (size_t)b * 4 * HW + base;
    float v0 = p[0], v1 = p[HW], v2 = p[2 * HW], v3 = p[3 * HW];
    int y = base / W, x = base - y * W;
    float px = x * s, py = y * s;
    float cx = v0 * s + px, cy = v1 * s + py;
    float w = expf(v2) * s, h = expf(v3) * s;
    boxes[t] = make_float4(cx - w * 0.5f, cy - h * 0.5f, cx + w * 0.5f, cy + h * 0.5f);
}

__device__ __forceinline__ bool iou_gt(float4 a, float4 c) {
    float tlx = fmaxf(a.x, c.x), tly = fmaxf(a.y, c.y);
    float brx = fminf(a.z, c.z), bry = fminf(a.w, c.w);
    float w = fmaxf(brx - tlx, 0.f), h = fmaxf(bry - tly, 0.f);
    float inter = w * h;
    float a1 = (a.z - a.x) * (a.w - a.y);
    float a2 = (c.z - c.x) * (c.w - c.y);
    return inter / (a1 + a2 - inter + 1e-6f) > 0.65f;
}

__device__ __forceinline__ unsigned long long wave_max_u64(unsigned long long v) {
    #pragma unroll
    for (int d = 32; d > 0; d >>= 1) {
        int lo = __shfl_xor((int)(uint32_t)v, d);
        int hi = __shfl_xor((int)(uint32_t)(v >> 32), d);
        unsigned long long o = ((unsigned long long)(uint32_t)hi << 32) | (uint32_t)lo;
        if (o > v) v = o;
    }
    return v;
}

// ================================================================ per-WAVE select + sort + NMS (no __syncthreads)
__global__ __launch_bounds__(256)
void select_nms_wave(const float* __restrict__ cls0, const float* __restrict__ obj0,
                     const float* __restrict__ cls1, const float* __restrict__ obj1,
                     const float* __restrict__ cls2, const float* __restrict__ obj2,
                     const float4* __restrict__ boxes,
                     float* __restrict__ keptScore, float4* __restrict__ keptBox) {
    __shared__ uint32_t sHist[4 * 1024];                 // 16 KB (overlaid by sorted arrays)
    __shared__ unsigned long long cPackA[4 * CAPF];      // 16 KB
    __shared__ float4 bBoxA[4 * 256];                    // 16 KB

    int tid = threadIdx.x, lane = tid & 63, wv = tid >> 6;
    int task = blockIdx.x * 4 + wv;                      // 640 tasks
    int b = task / NCLS, c = task - b * NCLS;

    uint32_t* hist = &sHist[wv * 1024];
    unsigned long long* cPack = &cPackA[wv * CAPF];
    float4* bBoxL = &bBoxA[wv * 256];
    uint32_t* sKeyS = (uint32_t*)&sHist[wv * 1024];          // overlay (after hist is dead)
    uint16_t* sIdxS = (uint16_t*)&sHist[wv * 1024 + 512];

    // ---- exact radix threshold selection, wave-private hist, levels 10/10/10/2 bits
    uint32_t prefix = 0, carry = 0, Tsel = 0;
    for (int level = 0;; ++level) {
        int shift = (level == 0) ? 22 : (level == 1) ? 12 : (level == 2) ? 2 : 0;
        int nb = (level == 3) ? 4 : 1024;
        // zero
        #pragma unroll 4
        for (int j = 0; j < 16; ++j) hist[lane * 16 + j] = 0;
        // histogram (keys recomputed)
        for (int i = 0; i < NITER; ++i) {
            int n = i * 64 + lane;
            if (n < NPTS) {
                uint32_t k = score_key(n, b, c, cls0, obj0, cls1, obj1, cls2, obj2);
                if (k > THRBITS) {
                    bool in = true;
                    if (level == 1) in = (k >> 22) == (prefix >> 22);
                    else if (level == 2) in = (k >> 12) == (prefix >> 12);
                    else if (level == 3) in = (k >> 2) == (prefix >> 2);
                    if (in) {
                        uint32_t bin = (level == 3) ? (k & 3u) : ((k >> shift) & 1023u);
                        atomicAdd(&hist[bin], 1u);
                    }
                }
            }
        }
        // scan: suffix over lanes (16 bins/lane for nb=1024)
        uint32_t lsum = 0;
        if (nb == 1024) {
            #pragma unroll 4
            for (int j = 0; j < 16; ++j) lsum += hist[lane * 16 + j];
        } else {
            lsum = (lane < 4) ? hist[lane] : 0u;
        }
        uint32_t suf = lsum;
        #pragma unroll
        for (int d = 1; d < 64; d <<= 1) {
            uint32_t t = (uint32_t)__shfl_down((int)suf, d);
            if (lane + d < 64) suf += t;
        }
        unsigned long long m = __ballot(carry + suf >= NEEDF);
        if (!m) { Tsel = 0; break; }                     // take-all (total < need <= cap)
        int l1 = 63 - __clzll(m);
        uint32_t carry2 = carry + (uint32_t)__shfl((int)suf, l1) - (uint32_t)__shfl((int)lsum, l1);
        int top = (nb == 1024) ? (l1 * 16 + 15) : l1;
        int bot = (nb == 1024) ? (l1 * 16) : l1;
        uint32_t acc = carry2, bCnt = 0; int bin = bot;
        for (int bb = top; bb >= bot; --bb) {
            uint32_t cc = hist[bb];                      // same addr all lanes: broadcast
            if (acc + cc >= NEEDF) { bin = bb; bCnt = cc; break; }
            acc += cc;
        }
        uint32_t cntIncl = acc + bCnt;
        if (cntIncl <= CAPF) { Tsel = prefix | ((uint32_t)bin << shift); break; }
        if (level == 3)      { Tsel = (prefix | (uint32_t)bin) + 1u; break; }  // exclude exact tie-key; continuation recovers
        prefix |= (uint32_t)bin << shift;
        carry = acc;
    }

    // ---- compact: packed u64 (key<<32 | (0xFFFF - n)) => order = pack desc
    uint32_t base = 0;
    for (int i = 0; i < NITER; ++i) {
        int n = i * 64 + lane;
        bool pred = false; uint32_t k = 0;
        if (n < NPTS) {
            k = score_key(n, b, c, cls0, obj0, cls1, obj1, cls2, obj2);
            pred = (k > THRBITS && k >= Tsel);
        }
        unsigned long long msk = __ballot(pred);
        uint32_t pos = base + (uint32_t)__popcll(msk & ((1ull << lane) - 1ull));
        if (pred && pos < CAPF)
            cPack[pos] = ((unsigned long long)k << 32) | (uint32_t)(0xFFFFu - n);
        base += (uint32_t)__popcll(msk);
    }
    int cnt = (base < CAPF) ? (int)base : CAPF;

    // ---- rank-sort (wave-internal; broadcast reads)
    {
        unsigned long long v[8]; int r[8];
        #pragma unroll
        for (int q = 0; q < 8; ++q) {
            int s = q * 64 + lane;
            v[q] = (s < cnt) ? cPack[s] : 0ull;
            r[q] = 0;
        }
        for (int j = 0; j < cnt; ++j) {
            unsigned long long w = cPack[j];             // broadcast
            #pragma unroll
            for (int q = 0; q < 8; ++q) r[q] += (w > v[q]) ? 1 : 0;
        }
        #pragma unroll
        for (int q = 0; q < 8; ++q) {
            int s = q * 64 + lane;
            if (s < cnt) {
                sKeyS[r[q]] = (uint32_t)(v[q] >> 32);
                sIdxS[r[q]] = (uint16_t)(0xFFFFu - (uint32_t)(v[q] & 0xFFFFu));
            }
        }
    }

    // ---- gather candidate boxes (first 256 sorted) into wave-private LDS
    #pragma unroll
    for (int q = 0; q < 4; ++q) {
        int s = q * 64 + lane;
        if (s < cnt && s < 256) bBoxL[s] = boxes[(size_t)b * NPTS + sIdxS[s]];
    }

    // ---- serial greedy walk: kept set distributed in lane registers
    float4 kb0 = make_float4(0.f, 0.f, 0.f, 0.f), kb1 = kb0;
    float ks0 = -1.0f, ks1 = -1.0f;
    int K = 0;
    for (int p = 0; p < cnt && K < KEEP; ++p) {
        float4 bx;
        if (p < 256) bx = bBoxL[p];                      // broadcast b128
        else         bx = boxes[(size_t)b * NPTS + sIdxS[p]];   // rare
        bool sup = false;
        if (lane < K)      sup = iou_gt(bx, kb0);
        if (64 + lane < K) sup = sup || iou_gt(bx, kb1);
        if (!__any(sup ? 1 : 0)) {
            float sc = __uint_as_float(sKeyS[p]);
            if (K < 64) { if (lane == K)      { kb0 = bx; ks0 = sc; } }
            else        { if (lane == K - 64) { kb1 = bx; ks1 = sc; } }
            K++;
        }
    }

    // ---- exact continuation (rare): wave argmax over remaining keys
    if (K < KEEP) {
        uint32_t cK = (cnt > 0) ? sKeyS[cnt - 1] : 0xFFFFFFFFu;
        uint32_t cI = (cnt > 0) ? (uint32_t)sIdxS[cnt - 1] : 0xFFFFFFFFu;
        int e = cnt;
        while (K < KEEP && e < PRETOPK) {
            unsigned long long best = 0ull;
            for (int i = 0; i < NITER; ++i) {
                int n = i * 64 + lane;
                if (n < NPTS) {
                    uint32_t k = score_key(n, b, c, cls0, obj0, cls1, obj1, cls2, obj2);
                    if (k > THRBITS && (k < cK || (k == cK && (uint32_t)n > cI))) {
                        unsigned long long v = ((unsigned long long)k << 32) | (uint32_t)(NPTS - 1 - n);
                        if (v > best) best = v;
                    }
                }
            }
            best = wave_max_u64(best);
            if (best == 0ull) break;
            uint32_t k = (uint32_t)(best >> 32);
            int n = NPTS - 1 - (int)(best & 0xFFFFFFFFull);
            float4 bx = boxes[(size_t)b * NPTS + n];
            bool sup = false;
            if (lane < K)      sup = iou_gt(bx, kb0);
            if (64 + lane < K) sup = sup || iou_gt(bx, kb1);
            if (!__any(sup ? 1 : 0)) {
                float sc = __uint_as_float(k);
                if (K < 64) { if (lane == K)      { kb0 = bx; ks0 = sc; } }
                else        { if (lane == K - 64) { kb1 = bx; ks1 = sc; } }
                K++;
            }
            e++; cK = k; cI = (uint32_t)n;
        }
    }

    // ---- write per-class results
    int off = (b * NCLS + c) * KEEP;
    float4 z = make_float4(0.f, 0.f, 0.f, 0.f);
    keptScore[off + lane] = (lane < K) ? ks0 : -1.0f;
    keptBox[off + lane]   = (lane < K) ? kb0 : z;
    if (64 + lane < KEEP) {
        keptScore[off + 64 + lane] = (64 + lane < K) ? ks1 : -1.0f;
        keptBox[off + 64 + lane]   = (64 + lane < K) ? kb1 : z;
    }
}

// ---------------------------------------------------------------- topk (R6-proven, verbatim)
__device__ void scan_cross_fast(const uint32_t* hist, int nb, uint32_t need, uint32_t cap,
                                uint32_t carry, uint32_t prefix, int shift, int level,
                                uint32_t* shr, int lane) {
    uint32_t csum;
    if (nb == 4096) {
        uint32_t s = 0;
        int cb = lane << 6;
        #pragma unroll 8
        for (int i = 0; i < 64; ++i) s += hist[cb + i];
        csum = s;
    } else {
        csum = hist[lane];
    }
    uint32_t suf = csum;
    #pragma unroll
    for (int d = 1; d < 64; d <<= 1) {
        uint32_t t = (uint32_t)__shfl_down((int)suf, d);
        if (lane + d < 64) suf += t;
    }
    unsigned long long m = __ballot(carry + suf >= need);
    if (!m) { if (lane == 0) { shr[1] = 0u; shr[0] = 0u; } return; }
    int l1 = 63 - __clzll(m);
    uint32_t sufL1 = (uint32_t)__shfl((int)suf, l1);
    uint32_t csumL1 = (uint32_t)__shfl((int)csum, l1);
    uint32_t carry2 = carry + sufL1 - csumL1;
    int foundBin; uint32_t cAbove, bCnt;
    if (nb == 4096) {
        int cb = l1 << 6;
        uint32_t c2 = hist[cb + lane];
        uint32_t suf2 = c2;
        #pragma unroll
        for (int d = 1; d < 64; d <<= 1) {
            uint32_t t = (uint32_t)__shfl_down((int)suf2, d);
            if (lane + d < 64) suf2 += t;
        }
        unsigned long long m2 = __ballot(carry2 + suf2 >= need);
        int l2 = 63 - __clzll(m2);
        foundBin = cb + l2;
        uint32_t suf2L = (uint32_t)__shfl((int)suf2, l2);
        uint32_t c2L = (uint32_t)__shfl((int)c2, l2);
        cAbove = carry2 + suf2L - c2L;
        bCnt = c2L;
    } else {
        foundBin = l1; cAbove = carry2; bCnt = csumL1;
    }
    if (lane == 0) {
        uint32_t cntIncl = cAbove + bCnt;
        if (cntIncl <= cap) { shr[1] = 0u; shr[0] = prefix | ((uint32_t)foundBin << shift); }
        else if (level == 2) { shr[1] = 0u; shr[0] = (prefix | (uint32_t)foundBin) + 1u; }
        else { shr[1] = 1u; shr[2] = prefix | ((uint32_t)foundBin << shift); shr[3] = cAbove; }
    }
}

__global__ __launch_bounds__(TBT)
void topk_out(const float* __restrict__ keptScore, const float4* __restrict__ keptBox,
              float* __restrict__ out) {
    __shared__ uint32_t sHist[4096];
    __shared__ uint32_t cKey[CAPT];
    __shared__ uint16_t cIdx[CAPT];
    __shared__ uint32_t sKeyS[CAPT];
    __shared__ uint16_t sIdxS[CAPT];
    __shared__ uint32_t shr[4];
    int b = blockIdx.x, tid = threadIdx.x, lane = tid & 63;
    const int TOT = NCLS * KEEP;

    uint32_t rKey[NREGT];
    #pragma unroll
    for (int i = 0; i < NREGT; ++i) {
        int n = tid + i * TBT;
        uint32_t key = 0u;
        if (n < TOT) {
            float s = keptScore[b * TOT + n];
            key = (s > 0.f) ? __float_as_uint(s) : 0u;
        }
        rKey[i] = key;
    }

    uint32_t prefix = 0, carry = 0, Tsel = 0;
    for (int level = 0;; ++level) {
        int shift = (level == 0) ? 18 : (level == 1 ? 6 : 0);
        int nb = (level == 2) ? 64 : 4096;
        __syncthreads();
        for (int i = tid; i < nb; i += TBT) sHist[i] = 0;
        __syncthreads();
        #pragma unroll
        for (int i = 0; i < NREGT; ++i) {
            uint32_t k = rKey[i];
            if (k > 0u) {
                if (level == 0) atomicAdd(&sHist[k >> 18], 1u);
                else if (level == 1) { if ((k >> 18) == (prefix >> 18)) atomicAdd(&sHist[(k >> 6) & 0xFFFu], 1u); }
                else { if ((k >> 6) == (prefix >> 6)) atomicAdd(&sHist[k & 0x3Fu], 1u); }
            }
        }
        __syncthreads();
        if (tid < 64) scan_cross_fast(sHist, nb, (uint32_t)KEEP, CAPT, carry, prefix, shift, level, shr, lane);
        __syncthreads();
        if (shr[1] == 0u) { Tsel = shr[0]; break; }
        prefix = shr[2]; carry = shr[3];
    }
    __syncthreads();
    if (tid == 0) shr[3] = 0u;
    __syncthreads();
    #pragma unroll
    for (int i = 0; i < NREGT; ++i) {
        uint32_t k = rKey[i];
        if (k > 0u && k >= Tsel) {
            uint32_t s = atomicAdd(&shr[3], 1u);
            if (s < CAPT) { cKey[s] = k; cIdx[s] = (uint16_t)(tid + i * TBT); }
        }
    }
    __syncthreads();
    int cnt = (int)shr[3]; if (cnt > CAPT) cnt = CAPT;

    {
        uint32_t k0 = 0; uint16_t i0 = 0; int r0 = 0;
        bool h0 = tid < cnt;
        if (h0) { k0 = cKey[tid]; i0 = cIdx[tid]; }
        for (int j = 0; j < cnt; ++j) {
            uint32_t kj = cKey[j]; uint16_t ij = cIdx[j];
            if (h0) r0 += (kj > k0) || (kj == k0 && ij < i0);
        }
        __syncthreads();
        if (h0) { sKeyS[r0] = k0; sIdxS[r0] = i0; }
        __syncthreads();
    }

    if (tid < KEEP) {
        bool valid = tid < cnt;
        int fi = valid ? (int)sIdxS[tid] : 0;
        float sc = valid ? __uint_as_float(sKeyS[tid]) : 0.f;
        float4 bx = valid ? keptBox[b * TOT + fi] : make_float4(0.f, 0.f, 0.f, 0.f);
        float cls = valid ? (float)(fi / KEEP) : -1.0f;
        float* boxOut = out + NB + (b * KEEP + tid) * 4;
        boxOut[0] = bx.x; boxOut[1] = bx.y; boxOut[2] = bx.z; boxOut[3] = bx.w;
        out[NB + NB * KEEP * 4 + b * KEEP + tid] = sc;
        out[NB + NB * KEEP * 4 + NB * KEEP + b * KEEP + tid] = cls;
    }
    if (tid == 0) out[b] = (float)((cnt < KEEP) ? cnt : KEEP);
}

// ---------------------------------------------------------------- launch
extern "C" void kernel_launch(void* const* d_in, const int* in_sizes, int n_in,
                              void* d_out, int out_size, void* d_ws, size_t ws_size,
                              hipStream_t stream) {
    const float* cls0 = (const float*)d_in[0];
    const float* bb0  = (const float*)d_in[1];
    const float* obj0 = (const float*)d_in[2];
    const float* cls1 = (const float*)d_in[3];
    const float* bb1  = (const float*)d_in[4];
    const float* obj1 = (const float*)d_in[5];
    const float* cls2 = (const float*)d_in[6];
    const float* bb2  = (const float*)d_in[7];
    const float* obj2 = (const float*)d_in[8];
    float* out = (float*)d_out;

    char* ws = (char*)d_ws;
    float4* boxes     = (float4*)(ws);                 // 1,075,200 B
    float*  keptScore = (float*)(ws + 1075200);        //   256,000 B
    float4* keptBox   = (float4*)(ws + 1331200);       // 1,024,000 B

    decode_boxes<<<(NB * NPTS + 255) / 256, 256, 0, stream>>>(bb0, bb1, bb2, boxes);
    select_nms_wave<<<160, 256, 0, stream>>>(cls0, obj0, cls1, obj1, cls2, obj2,
                                             boxes, keptScore, keptBox);
    topk_out<<<NB, TBT, 0, stream>>>(keptScore, keptBox, out);
}

// Round 10
// 212.189 us; speedup vs baseline: 1.6096x; 1.6096x over previous
//
#include <hip/hip_runtime.h>
#include <math.h>
#include <stdint.h>

#define NCLS   80
#define NPTS   8400
#define KEEP   100
#define PRETOPK 5000
#define NB     8
#define THRBITS 0x3C23D70Au   // bits of 0.01f (scores positive floats -> int-ordered)

#define TBS    512            // select block size
#define NREG   17             // ceil(8400/512)
#define CAPF   512            // candidate cap
#define NEEDF  192u           // selection target
#define MTX    256            // suppression-matrix size

#define TBT    1024           // topk block size
#define NREGT  8              // 8000/1024
#define CAPT   512

__device__ __forceinline__ float sigmoidf_(float x) { return 1.0f / (1.0f + expf(-x)); }

__device__ __forceinline__ uint32_t score_key(int n, int b, int c,
        const float* cls0, const float* obj0, const float* cls1, const float* obj1,
        const float* cls2, const float* obj2) {
    const float *clsP, *objP; int base, HW;
    if (n < 6400)      { clsP = cls0; objP = obj0; base = n;        HW = 6400; }
    else if (n < 8000) { clsP = cls1; objP = obj1; base = n - 6400; HW = 1600; }
    else               { clsP = cls2; objP = obj2; base = n - 8000; HW = 400;  }
    float cv = clsP[((size_t)b * NCLS + c) * HW + base];
    float ov = objP[(size_t)b * HW + base];
    return __float_as_uint(sigmoidf_(cv) * sigmoidf_(ov));
}

__device__ __forceinline__ float4 decode_one(int n, int b,
        const float* bb0, const float* bb1, const float* bb2) {
    const float* bb; int base, HW, x, y; float s;
    if (n < 6400)      { bb = bb0; base = n;        HW = 6400; s = 8.f;  y = base / 80; x = base - y * 80; }
    else if (n < 8000) { bb = bb1; base = n - 6400; HW = 1600; s = 16.f; y = base / 40; x = base - y * 40; }
    else               { bb = bb2; base = n - 8000; HW = 400;  s = 32.f; y = base / 20; x = base - y * 20; }
    const float* p = bb + (size_t)b * 4 * HW + base;
    float v0 = p[0], v1 = p[HW], v2 = p[2 * HW], v3 = p[3 * HW];
    float cx = v0 * s + x * s, cy = v1 * s + y * s;
    float w = expf(v2) * s, h = expf(v3) * s;
    return make_float4(cx - 0.5f * w, cy - 0.5f * h, cx + 0.5f * w, cy + 0.5f * h);
}

__device__ __forceinline__ bool iou_gt(float4 a, float4 c) {
    float tlx = fmaxf(a.x, c.x), tly = fmaxf(a.y, c.y);
    float brx = fminf(a.z, c.z), bry = fminf(a.w, c.w);
    float w = fmaxf(brx - tlx, 0.f), h = fmaxf(bry - tly, 0.f);
    float inter = w * h;
    float a1 = (a.z - a.x) * (a.w - a.y);
    float a2 = (c.z - c.x) * (c.w - c.y);
    return inter / (a1 + a2 - inter + 1e-6f) > 0.65f;
}

// ================================================================ fused per-(b,c) select + sort + NMS
__global__ __launch_bounds__(TBS)
void select_nms(const float* __restrict__ cls0, const float* __restrict__ bb0, const float* __restrict__ obj0,
                const float* __restrict__ cls1, const float* __restrict__ bb1, const float* __restrict__ obj1,
                const float* __restrict__ cls2, const float* __restrict__ bb2, const float* __restrict__ obj2,
                float* __restrict__ keptScore, float4* __restrict__ keptBox) {
    __shared__ uint32_t sHist[1024];                             // 4 KB
    __shared__ __align__(16) unsigned long long cPack[CAPF + 16]; // 4.2 KB
    __shared__ uint32_t sKeyS[CAPF];                             // 2 KB
    __shared__ uint16_t sIdxS[CAPF];                             // 1 KB
    __shared__ float4   bBoxS[CAPF];                             // 8 KB
    __shared__ unsigned long long colM[MTX][4];                  // 8 KB
    __shared__ uint32_t shr[4];
    __shared__ unsigned long long sh64;

    int bc = blockIdx.x;
    int b = bc / NCLS, c = bc - b * NCLS;
    int tid = threadIdx.x, lane = tid & 63;

    // ---- phase 1: keygen into registers
    uint32_t rKey[NREG];
    #pragma unroll
    for (int i = 0; i < NREG; ++i) {
        int n = tid + i * TBS;
        rKey[i] = (n < NPTS) ? score_key(n, b, c, cls0, obj0, cls1, obj1, cls2, obj2) : 0u;
    }

    // ---- phase 2: exact radix threshold selection (levels 10/10/10/2 bits)
    uint32_t prefix = 0, carry = 0, Tsel = 0;
    for (int level = 0;; ++level) {
        int shift = (level == 0) ? 22 : (level == 1) ? 12 : (level == 2) ? 2 : 0;
        bool nb4 = (level == 3);
        __syncthreads();
        if (!nb4) { sHist[tid] = 0; sHist[tid + 512] = 0; }
        else if (tid < 4) sHist[tid] = 0;
        __syncthreads();
        #pragma unroll
        for (int i = 0; i < NREG; ++i) {
            uint32_t k = rKey[i];
            if (k > THRBITS) {
                if (level == 0) atomicAdd(&sHist[k >> 22], 1u);
                else if (level == 1) { if ((k >> 22) == (prefix >> 22)) atomicAdd(&sHist[(k >> 12) & 1023u], 1u); }
                else if (level == 2) { if ((k >> 12) == (prefix >> 12)) atomicAdd(&sHist[(k >> 2) & 1023u], 1u); }
                else { if ((k >> 2) == (prefix >> 2)) atomicAdd(&sHist[k & 3u], 1u); }
            }
        }
        __syncthreads();
        if (tid < 64) {
            if (!nb4) {
                const uint4* hv = (const uint4*)sHist;
                uint4 q0 = hv[lane * 4], q1 = hv[lane * 4 + 1], q2 = hv[lane * 4 + 2], q3 = hv[lane * 4 + 3];
                uint32_t csum = q0.x + q0.y + q0.z + q0.w + q1.x + q1.y + q1.z + q1.w
                              + q2.x + q2.y + q2.z + q2.w + q3.x + q3.y + q3.z + q3.w;
                uint32_t suf = csum;
                #pragma unroll
                for (int d = 1; d < 64; d <<= 1) {
                    uint32_t t = (uint32_t)__shfl_down((int)suf, d);
                    if (lane + d < 64) suf += t;
                }
                unsigned long long m = __ballot(carry + suf >= NEEDF);
                if (!m) { if (lane == 0) { shr[1] = 0u; shr[0] = 0u; } }
                else {
                    int l1 = 63 - __clzll(m);
                    uint32_t carry2 = carry + (uint32_t)__shfl((int)suf, l1) - (uint32_t)__shfl((int)csum, l1);
                    uint4 b0 = hv[l1 * 4], b1 = hv[l1 * 4 + 1], b2 = hv[l1 * 4 + 2], b3 = hv[l1 * 4 + 3];
                    uint32_t v[16] = {b0.x, b0.y, b0.z, b0.w, b1.x, b1.y, b1.z, b1.w,
                                      b2.x, b2.y, b2.z, b2.w, b3.x, b3.y, b3.z, b3.w};
                    uint32_t acc = carry2, bCnt = 0; int bin = l1 * 16;
                    #pragma unroll
                    for (int t = 15; t >= 0; --t) {
                        uint32_t cc = v[t];
                        if (acc + cc >= NEEDF) { bin = l1 * 16 + t; bCnt = cc; break; }
                        acc += cc;
                    }
                    uint32_t cntIncl = acc + bCnt;
                    if (lane == 0) {
                        if (cntIncl <= CAPF) { shr[1] = 0u; shr[0] = prefix | ((uint32_t)bin << shift); }
                        else { shr[1] = 1u; shr[2] = prefix | ((uint32_t)bin << shift); shr[3] = acc; }
                    }
                }
            } else {
                uint32_t v0 = sHist[0], v1 = sHist[1], v2 = sHist[2], v3 = sHist[3];
                uint32_t v[4] = {v0, v1, v2, v3};
                uint32_t acc = carry, bCnt = 0; int bin = 0;
                #pragma unroll
                for (int t = 3; t >= 0; --t) {
                    uint32_t cc = v[t];
                    if (acc + cc >= NEEDF) { bin = t; bCnt = cc; break; }
                    acc += cc;
                }
                uint32_t cntIncl = acc + bCnt;
                if (lane == 0) {
                    shr[1] = 0u;
                    if (cntIncl <= CAPF) shr[0] = prefix | (uint32_t)bin;
                    else shr[0] = (prefix | (uint32_t)bin) + 1u;   // exclude exact tie-key; continuation recovers
                }
            }
        }
        __syncthreads();
        if (shr[1] == 0u) { Tsel = shr[0]; break; }
        prefix = shr[2]; carry = shr[3];
    }
    __syncthreads();
    if (tid == 0) shr[3] = 0u;
    __syncthreads();

    // ---- phase 3: compact (packed u64: key<<32 | (0xFFFF - n) => order = pack desc)
    #pragma unroll
    for (int i = 0; i < NREG; ++i) {
        uint32_t k = rKey[i];
        if (k > THRBITS && k >= Tsel) {
            uint32_t s = atomicAdd(&shr[3], 1u);
            if (s < CAPF) cPack[s] = ((unsigned long long)k << 32) | (uint32_t)(0xFFFFu - (tid + i * TBS));
        }
    }
    __syncthreads();
    int cnt = (int)shr[3]; if (cnt > CAPF) cnt = CAPF;
    if (tid < 16) cPack[cnt + tid] = 0ull;
    __syncthreads();

    // ---- phase 4: rank-sort, 16 candidates per iteration (batched b128 reads)
    {
        bool h0 = tid < cnt;
        unsigned long long my = h0 ? cPack[tid] : 0ull;
        int r0 = 0;
        const ulonglong2* cp2 = (const ulonglong2*)cPack;
        int nb16 = (cnt + 15) >> 4;
        for (int jb = 0; jb < nb16; ++jb) {
            ulonglong2 p0 = cp2[jb * 8 + 0], p1 = cp2[jb * 8 + 1], p2 = cp2[jb * 8 + 2], p3 = cp2[jb * 8 + 3];
            ulonglong2 p4 = cp2[jb * 8 + 4], p5 = cp2[jb * 8 + 5], p6 = cp2[jb * 8 + 6], p7 = cp2[jb * 8 + 7];
            r0 += (p0.x > my) + (p0.y > my) + (p1.x > my) + (p1.y > my)
                + (p2.x > my) + (p2.y > my) + (p3.x > my) + (p3.y > my)
                + (p4.x > my) + (p4.y > my) + (p5.x > my) + (p5.y > my)
                + (p6.x > my) + (p6.y > my) + (p7.x > my) + (p7.y > my);
        }
        if (h0) {
            sKeyS[r0] = (uint32_t)(my >> 32);
            sIdxS[r0] = (uint16_t)(0xFFFFu - (uint32_t)(my & 0xFFFFu));
        }
        __syncthreads();
    }

    // ---- phase 5: gather + inline-decode candidate boxes
    for (int s = tid; s < cnt; s += TBS) bBoxS[s] = decode_one(sIdxS[s], b, bb0, bb1, bb2);
    __syncthreads();

    // ---- phase 6: column suppression bitmatrix, tiled over 8 waves
    int lim = (cnt < MTX) ? cnt : MTX;
    {
        int w = tid >> 6, l = lane;
        const int fullCg[6] = {1, 2, 2, 3, 3, 3};
        const int fullRb[6] = {0, 0, 1, 0, 1, 2};
        if (w < 6) {
            int cg = fullCg[w], rb = fullRb[w];
            int cand = (cg << 6) + l;
            unsigned long long m = 0ull;
            if (cand < lim) {
                float4 bcx = bBoxS[cand];
                int j0 = rb << 6;
                #pragma unroll 8
                for (int jj = 0; jj < 64; ++jj)
                    if (iou_gt(bBoxS[j0 + jj], bcx)) m |= 1ull << jj;
            }
            colM[(cg << 6) + l][rb] = m;
        } else {
            int d0 = (w == 6) ? 0 : 1;
            #pragma unroll
            for (int t = 0; t < 2; ++t) {
                int cg = d0 + 2 * t;
                int cand = (cg << 6) + l;
                unsigned long long m = 0ull;
                if (cand < lim) {
                    float4 bcx = bBoxS[cand];
                    int j0 = cg << 6;
                    #pragma unroll 4
                    for (int jj = 0; jj < l; ++jj)
                        if (iou_gt(bBoxS[j0 + jj], bcx)) m |= 1ull << jj;
                }
                colM[(cg << 6) + l][cg] = m;
            }
        }
    }
    __syncthreads();

    // ---- phase 7: serial walk on wave 0 — ballot + register bit ops only
    float4 kb0 = make_float4(0.f, 0.f, 0.f, 0.f), kb1 = kb0;
    float ks0 = -1.0f, ks1 = -1.0f;
    int K = 0;
    if (tid < 64) {
        unsigned long long cA[4], cB[4], cC[4], cD[4];
        #pragma unroll
        for (int rb = 0; rb < 4; ++rb) {
            cA[rb] = colM[lane][rb];
            cB[rb] = colM[64 + lane][rb];
            cC[rb] = colM[128 + lane][rb];
            cD[rb] = colM[192 + lane][rb];
        }
        bool a0 = lane < lim, a1 = 64 + lane < lim, a2 = 128 + lane < lim, a3 = 192 + lane < lim;
        int kIA = -1, kIB = -1;
        while (K < KEEP) {
            unsigned long long m0 = __ballot(a0);
            unsigned long long m1 = __ballot(a1);
            unsigned long long m2 = __ballot(a2);
            unsigned long long m3 = __ballot(a3);
            int i;
            if (m0)      i = (int)__ffsll(m0) - 1;
            else if (m1) i = 64 + (int)__ffsll(m1) - 1;
            else if (m2) i = 128 + (int)__ffsll(m2) - 1;
            else if (m3) i = 192 + (int)__ffsll(m3) - 1;
            else break;
            int rb = i >> 6, il = i & 63;
            unsigned long long w0, w1, w2, w3;
            if (rb == 0)      { w0 = cA[0]; w1 = cB[0]; w2 = cC[0]; w3 = cD[0]; }
            else if (rb == 1) { w0 = cA[1]; w1 = cB[1]; w2 = cC[1]; w3 = cD[1]; }
            else if (rb == 2) { w0 = cA[2]; w1 = cB[2]; w2 = cC[2]; w3 = cD[2]; }
            else              { w0 = cA[3]; w1 = cB[3]; w2 = cC[3]; w3 = cD[3]; }
            if (rb == 0      && lane == il) a0 = false;
            else if (rb == 1 && lane == il) a1 = false;
            else if (rb == 2 && lane == il) a2 = false;
            else if (rb == 3 && lane == il) a3 = false;
            a0 = a0 && !((w0 >> il) & 1ull);
            a1 = a1 && !((w1 >> il) & 1ull);
            a2 = a2 && !((w2 >> il) & 1ull);
            a3 = a3 && !((w3 >> il) & 1ull);
            if (K < 64) { if (lane == K) kIA = i; }
            else        { if (lane == K - 64) kIB = i; }
            K++;
        }
        if (kIA >= 0) { kb0 = bBoxS[kIA]; ks0 = __uint_as_float(sKeyS[kIA]); }
        if (kIB >= 0) { kb1 = bBoxS[kIB]; ks1 = __uint_as_float(sKeyS[kIB]); }
        // mid-walk beyond matrix (cnt > MTX; rare)
        for (int i = lim; i < cnt && K < KEEP; ++i) {
            float4 bx = bBoxS[i];
            bool sup = false;
            if (lane < K)      sup = iou_gt(bx, kb0);
            if (64 + lane < K) sup = sup || iou_gt(bx, kb1);
            if (!__any(sup ? 1 : 0)) {
                float sc = __uint_as_float(sKeyS[i]);
                if (K < 64) { if (lane == K)      { kb0 = bx; ks0 = sc; } }
                else        { if (lane == K - 64) { kb1 = bx; ks1 = sc; } }
                K++;
            }
        }
        if (lane == 0) {
            shr[0] = (uint32_t)K;
            shr[1] = (uint32_t)cnt;
            shr[2] = (cnt > 0) ? sKeyS[cnt - 1] : 0xFFFFFFFFu;
            shr[3] = (cnt > 0) ? (uint32_t)sIdxS[cnt - 1] : 0xFFFFFFFFu;
        }
    }
    __syncthreads();
    int Kall = (int)shr[0]; int e = (int)shr[1];
    uint32_t cK = shr[2], cI = shr[3];

    // ---- phase 8: exact continuation via block argmax (rare)
    if (Kall < KEEP && e < PRETOPK) {
        for (;;) {
            if (tid == 0) sh64 = 0ull;
            __syncthreads();
            unsigned long long best = 0ull;
            #pragma unroll
            for (int i = 0; i < NREG; ++i) {
                uint32_t k = rKey[i]; int n = tid + i * TBS;
                if (k > THRBITS && (k < cK || (k == cK && (uint32_t)n > cI))) {
                    unsigned long long v = ((unsigned long long)k << 32) | (unsigned long long)(NPTS - 1 - n);
                    if (v > best) best = v;
                }
            }
            if (best) atomicMax(&sh64, best);
            __syncthreads();
            unsigned long long bv = sh64;
            if (bv == 0ull) break;
            uint32_t k = (uint32_t)(bv >> 32);
            int n = NPTS - 1 - (int)(bv & 0xFFFFFFFFull);
            if (tid < 64) {
                float4 bx = decode_one(n, b, bb0, bb1, bb2);
                bool sup = false;
                if (lane < K)      sup = iou_gt(bx, kb0);
                if (64 + lane < K) sup = sup || iou_gt(bx, kb1);
                if (!__any(sup ? 1 : 0)) {
                    float sc = __uint_as_float(k);
                    if (K < 64) { if (lane == K)      { kb0 = bx; ks0 = sc; } }
                    else        { if (lane == K - 64) { kb1 = bx; ks1 = sc; } }
                    K++;
                }
                if (lane == 0) shr[0] = (uint32_t)K;
            }
            __syncthreads();
            Kall = (int)shr[0];
            e++; cK = k; cI = (uint32_t)n;
            if (Kall >= KEEP || e >= PRETOPK) break;
        }
    }

    // ---- write per-class results
    if (tid < 64) {
        int off = (b * NCLS + c) * KEEP;
        float4 z = make_float4(0.f, 0.f, 0.f, 0.f);
        keptScore[off + lane] = (lane < K) ? ks0 : -1.0f;
        keptBox[off + lane]   = (lane < K) ? kb0 : z;
        if (64 + lane < KEEP) {
            keptScore[off + 64 + lane] = (64 + lane < K) ? ks1 : -1.0f;
            keptBox[off + 64 + lane]   = (64 + lane < K) ? kb1 : z;
        }
    }
}

// ---------------------------------------------------------------- topk (R6-proven scan; batched rank-sort)
__device__ void scan_cross_fast(const uint32_t* hist, int nb, uint32_t need, uint32_t cap,
                                uint32_t carry, uint32_t prefix, int shift, int level,
                                uint32_t* shr, int lane) {
    uint32_t csum;
    if (nb == 4096) {
        uint32_t s = 0;
        int cb = lane << 6;
        #pragma unroll 8
        for (int i = 0; i < 64; ++i) s += hist[cb + i];
        csum = s;
    } else {
        csum = hist[lane];
    }
    uint32_t suf = csum;
    #pragma unroll
    for (int d = 1; d < 64; d <<= 1) {
        uint32_t t = (uint32_t)__shfl_down((int)suf, d);
        if (lane + d < 64) suf += t;
    }
    unsigned long long m = __ballot(carry + suf >= need);
    if (!m) { if (lane == 0) { shr[1] = 0u; shr[0] = 0u; } return; }
    int l1 = 63 - __clzll(m);
    uint32_t sufL1 = (uint32_t)__shfl((int)suf, l1);
    uint32_t csumL1 = (uint32_t)__shfl((int)csum, l1);
    uint32_t carry2 = carry + sufL1 - csumL1;
    int foundBin; uint32_t cAbove, bCnt;
    if (nb == 4096) {
        int cb = l1 << 6;
        uint32_t c2 = hist[cb + lane];
        uint32_t suf2 = c2;
        #pragma unroll
        for (int d = 1; d < 64; d <<= 1) {
            uint32_t t = (uint32_t)__shfl_down((int)suf2, d);
            if (lane + d < 64) suf2 += t;
        }
        unsigned long long m2 = __ballot(carry2 + suf2 >= need);
        int l2 = 63 - __clzll(m2);
        foundBin = cb + l2;
        uint32_t suf2L = (uint32_t)__shfl((int)suf2, l2);
        uint32_t c2L = (uint32_t)__shfl((int)c2, l2);
        cAbove = carry2 + suf2L - c2L;
        bCnt = c2L;
    } else {
        foundBin = l1; cAbove = carry2; bCnt = csumL1;
    }
    if (lane == 0) {
        uint32_t cntIncl = cAbove + bCnt;
        if (cntIncl <= cap) { shr[1] = 0u; shr[0] = prefix | ((uint32_t)foundBin << shift); }
        else if (level == 2) { shr[1] = 0u; shr[0] = (prefix | (uint32_t)foundBin) + 1u; }
        else { shr[1] = 1u; shr[2] = prefix | ((uint32_t)foundBin << shift); shr[3] = cAbove; }
    }
}

__global__ __launch_bounds__(TBT)
void topk_out(const float* __restrict__ keptScore, const float4* __restrict__ keptBox,
              float* __restrict__ out) {
    __shared__ uint32_t sHist[4096];
    __shared__ __align__(16) unsigned long long cPackT[CAPT + 16];
    __shared__ uint32_t sKeyS[CAPT];
    __shared__ uint16_t sIdxS[CAPT];
    __shared__ uint32_t shr[4];
    int b = blockIdx.x, tid = threadIdx.x, lane = tid & 63;
    const int TOT = NCLS * KEEP;

    uint32_t rKey[NREGT];
    #pragma unroll
    for (int i = 0; i < NREGT; ++i) {
        int n = tid + i * TBT;
        uint32_t key = 0u;
        if (n < TOT) {
            float s = keptScore[b * TOT + n];
            key = (s > 0.f) ? __float_as_uint(s) : 0u;
        }
        rKey[i] = key;
    }

    uint32_t prefix = 0, carry = 0, Tsel = 0;
    for (int level = 0;; ++level) {
        int shift = (level == 0) ? 18 : (level == 1 ? 6 : 0);
        int nb = (level == 2) ? 64 : 4096;
        __syncthreads();
        for (int i = tid; i < nb; i += TBT) sHist[i] = 0;
        __syncthreads();
        #pragma unroll
        for (int i = 0; i < NREGT; ++i) {
            uint32_t k = rKey[i];
            if (k > 0u) {
                if (level == 0) atomicAdd(&sHist[k >> 18], 1u);
                else if (level == 1) { if ((k >> 18) == (prefix >> 18)) atomicAdd(&sHist[(k >> 6) & 0xFFFu], 1u); }
                else { if ((k >> 6) == (prefix >> 6)) atomicAdd(&sHist[k & 0x3Fu], 1u); }
            }
        }
        __syncthreads();
        if (tid < 64) scan_cross_fast(sHist, nb, (uint32_t)KEEP, CAPT, carry, prefix, shift, level, shr, lane);
        __syncthreads();
        if (shr[1] == 0u) { Tsel = shr[0]; break; }
        prefix = shr[2]; carry = shr[3];
    }
    __syncthreads();
    if (tid == 0) shr[3] = 0u;
    __syncthreads();
    #pragma unroll
    for (int i = 0; i < NREGT; ++i) {
        uint32_t k = rKey[i];
        if (k > 0u && k >= Tsel) {
            uint32_t s = atomicAdd(&shr[3], 1u);
            if (s < CAPT) cPackT[s] = ((unsigned long long)k << 32) | (uint32_t)(0xFFFFu - (tid + i * TBT));
        }
    }
    __syncthreads();
    int cnt = (int)shr[3]; if (cnt > CAPT) cnt = CAPT;
    if (tid < 16) cPackT[cnt + tid] = 0ull;
    __syncthreads();

    {
        bool h0 = tid < cnt;
        unsigned long long my = h0 ? cPackT[tid] : 0ull;
        int r0 = 0;
        const ulonglong2* cp2 = (const ulonglong2*)cPackT;
        int nb16 = (cnt + 15) >> 4;
        for (int jb = 0; jb < nb16; ++jb) {
            ulonglong2 p0 = cp2[jb * 8 + 0], p1 = cp2[jb * 8 + 1], p2 = cp2[jb * 8 + 2], p3 = cp2[jb * 8 + 3];
            ulonglong2 p4 = cp2[jb * 8 + 4], p5 = cp2[jb * 8 + 5], p6 = cp2[jb * 8 + 6], p7 = cp2[jb * 8 + 7];
            r0 += (p0.x > my) + (p0.y > my) + (p1.x > my) + (p1.y > my)
                + (p2.x > my) + (p2.y > my) + (p3.x > my) + (p3.y > my)
                + (p4.x > my) + (p4.y > my) + (p5.x > my) + (p5.y > my)
                + (p6.x > my) + (p6.y > my) + (p7.x > my) + (p7.y > my);
        }
        if (h0) {
            sKeyS[r0] = (uint32_t)(my >> 32);
            sIdxS[r0] = (uint16_t)(0xFFFFu - (uint32_t)(my & 0xFFFFu));
        }
        __syncthreads();
    }

    if (tid < KEEP) {
        bool valid = tid < cnt;
        int fi = valid ? (int)sIdxS[tid] : 0;
        float sc = valid ? __uint_as_float(sKeyS[tid]) : 0.f;
        float4 bx = valid ? keptBox[b * TOT + fi] : make_float4(0.f, 0.f, 0.f, 0.f);
        float cls = valid ? (float)(fi / KEEP) : -1.0f;
        float* boxOut = out + NB + (b * KEEP + tid) * 4;
        boxOut[0] = bx.x; boxOut[1] = bx.y; boxOut[2] = bx.z; boxOut[3] = bx.w;
        out[NB + NB * KEEP * 4 + b * KEEP + tid] = sc;
        out[NB + NB * KEEP * 4 + NB * KEEP + b * KEEP + tid] = cls;
    }
    if (tid == 0) out[b] = (float)((cnt < KEEP) ? cnt : KEEP);
}

// ---------------------------------------------------------------- launch
extern "C" void kernel_launch(void* const* d_in, const int* in_sizes, int n_in,
                              void* d_out, int out_size, void* d_ws, size_t ws_size,
                              hipStream_t stream) {
    const float* cls0 = (const float*)d_in[0];
    const float* bb0  = (const float*)d_in[1];
    const float* obj0 = (const float*)d_in[2];
    const float* cls1 = (const float*)d_in[3];
    const float* bb1  = (const float*)d_in[4];
    const float* obj1 = (const float*)d_in[5];
    const float* cls2 = (const float*)d_in[6];
    const float* bb2  = (const float*)d_in[7];
    const float* obj2 = (const float*)d_in[8];
    float* out = (float*)d_out;

    char* ws = (char*)d_ws;
    float*  keptScore = (float*)(ws);                  //   256,000 B
    float4* keptBox   = (float4*)(ws + 256000);        // 1,024,000 B

    select_nms<<<NB * NCLS, TBS, 0, stream>>>(cls0, bb0, obj0, cls1, bb1, obj1,
                                              cls2, bb2, obj2, keptScore, keptBox);
    topk_out<<<NB, TBT, 0, stream>>>(keptScore, keptBox, out);
}

// Round 11
// 211.059 us; speedup vs baseline: 1.6182x; 1.0054x over previous
//
#include <hip/hip_runtime.h>
#include <math.h>
#include <stdint.h>

#define NCLS   80
#define NPTS   8400
#define KEEP   100
#define PRETOPK 5000
#define NB     8
#define THRBITS 0x3C23D70Au   // bits of 0.01f (scores positive floats -> int-ordered)

#define TBS    1024           // select block size (16 waves; 2 blocks/CU -> 32 waves/CU)
#define NREG   9              // ceil(8400/1024)
#define CAPF   512            // candidate cap
#define NEEDF  192u           // selection target
#define MTX    256            // suppression-matrix size

#define TBT    1024           // topk block size
#define NREGT  8              // 8000/1024
#define CAPT   512

__device__ __forceinline__ float sigmoidf_(float x) { return 1.0f / (1.0f + expf(-x)); }

__device__ __forceinline__ uint32_t score_key(int n, int b, int c,
        const float* cls0, const float* obj0, const float* cls1, const float* obj1,
        const float* cls2, const float* obj2) {
    const float *clsP, *objP; int base, HW;
    if (n < 6400)      { clsP = cls0; objP = obj0; base = n;        HW = 6400; }
    else if (n < 8000) { clsP = cls1; objP = obj1; base = n - 6400; HW = 1600; }
    else               { clsP = cls2; objP = obj2; base = n - 8000; HW = 400;  }
    float cv = clsP[((size_t)b * NCLS + c) * HW + base];
    float ov = objP[(size_t)b * HW + base];
    return __float_as_uint(sigmoidf_(cv) * sigmoidf_(ov));
}

__device__ __forceinline__ float4 decode_one(int n, int b,
        const float* bb0, const float* bb1, const float* bb2) {
    const float* bb; int base, HW, x, y; float s;
    if (n < 6400)      { bb = bb0; base = n;        HW = 6400; s = 8.f;  y = base / 80; x = base - y * 80; }
    else if (n < 8000) { bb = bb1; base = n - 6400; HW = 1600; s = 16.f; y = base / 40; x = base - y * 40; }
    else               { bb = bb2; base = n - 8000; HW = 400;  s = 32.f; y = base / 20; x = base - y * 20; }
    const float* p = bb + (size_t)b * 4 * HW + base;
    float v0 = p[0], v1 = p[HW], v2 = p[2 * HW], v3 = p[3 * HW];
    float cx = v0 * s + x * s, cy = v1 * s + y * s;
    float w = expf(v2) * s, h = expf(v3) * s;
    return make_float4(cx - 0.5f * w, cy - 0.5f * h, cx + 0.5f * w, cy + 0.5f * h);
}

__device__ __forceinline__ bool iou_gt(float4 a, float4 c) {
    float tlx = fmaxf(a.x, c.x), tly = fmaxf(a.y, c.y);
    float brx = fminf(a.z, c.z), bry = fminf(a.w, c.w);
    float w = fmaxf(brx - tlx, 0.f), h = fmaxf(bry - tly, 0.f);
    float inter = w * h;
    float a1 = (a.z - a.x) * (a.w - a.y);
    float a2 = (c.z - c.x) * (c.w - c.y);
    return inter / (a1 + a2 - inter + 1e-6f) > 0.65f;
}

// ================================================================ fused per-(b,c) select + sort + NMS
__global__ __launch_bounds__(TBS, 8)
void select_nms(const float* __restrict__ cls0, const float* __restrict__ bb0, const float* __restrict__ obj0,
                const float* __restrict__ cls1, const float* __restrict__ bb1, const float* __restrict__ obj1,
                const float* __restrict__ cls2, const float* __restrict__ bb2, const float* __restrict__ obj2,
                float* __restrict__ keptScore, float4* __restrict__ keptBox) {
    __shared__ uint32_t sHist[1024];                             // 4 KB
    __shared__ __align__(16) unsigned long long cPack[CAPF + 16]; // 4.2 KB
    __shared__ uint32_t sKeyS[CAPF];                             // 2 KB
    __shared__ uint16_t sIdxS[CAPF];                             // 1 KB
    __shared__ float4   bBoxS[CAPF];                             // 8 KB
    __shared__ unsigned long long colM[MTX][4];                  // 8 KB
    __shared__ uint32_t shr[4];
    __shared__ unsigned long long sh64;

    int bc = blockIdx.x;
    int b = bc & 7;                  // XCD-locality: image b -> XCD b (blockIdx % 8)
    int c = bc >> 3;
    int tid = threadIdx.x, lane = tid & 63;

    // ---- phase 1: keygen into registers (9 loads/thread, coalesced)
    uint32_t rKey[NREG];
    #pragma unroll
    for (int i = 0; i < NREG; ++i) {
        int n = tid + i * TBS;
        rKey[i] = (n < NPTS) ? score_key(n, b, c, cls0, obj0, cls1, obj1, cls2, obj2) : 0u;
    }

    // ---- phase 2: exact radix threshold selection (levels 10/10/10/2 bits)
    uint32_t prefix = 0, carry = 0, Tsel = 0;
    for (int level = 0;; ++level) {
        int shift = (level == 0) ? 22 : (level == 1) ? 12 : (level == 2) ? 2 : 0;
        bool nb4 = (level == 3);
        __syncthreads();
        if (!nb4) sHist[tid] = 0;
        else if (tid < 4) sHist[tid] = 0;
        __syncthreads();
        #pragma unroll
        for (int i = 0; i < NREG; ++i) {
            uint32_t k = rKey[i];
            if (k > THRBITS) {
                if (level == 0) atomicAdd(&sHist[k >> 22], 1u);
                else if (level == 1) { if ((k >> 22) == (prefix >> 22)) atomicAdd(&sHist[(k >> 12) & 1023u], 1u); }
                else if (level == 2) { if ((k >> 12) == (prefix >> 12)) atomicAdd(&sHist[(k >> 2) & 1023u], 1u); }
                else { if ((k >> 2) == (prefix >> 2)) atomicAdd(&sHist[k & 3u], 1u); }
            }
        }
        __syncthreads();
        if (tid < 64) {
            if (!nb4) {
                const uint4* hv = (const uint4*)sHist;
                uint4 q0 = hv[lane * 4], q1 = hv[lane * 4 + 1], q2 = hv[lane * 4 + 2], q3 = hv[lane * 4 + 3];
                uint32_t csum = q0.x + q0.y + q0.z + q0.w + q1.x + q1.y + q1.z + q1.w
                              + q2.x + q2.y + q2.z + q2.w + q3.x + q3.y + q3.z + q3.w;
                uint32_t suf = csum;
                #pragma unroll
                for (int d = 1; d < 64; d <<= 1) {
                    uint32_t t = (uint32_t)__shfl_down((int)suf, d);
                    if (lane + d < 64) suf += t;
                }
                unsigned long long m = __ballot(carry + suf >= NEEDF);
                if (!m) { if (lane == 0) { shr[1] = 0u; shr[0] = 0u; } }
                else {
                    int l1 = 63 - __clzll(m);
                    uint32_t carry2 = carry + (uint32_t)__shfl((int)suf, l1) - (uint32_t)__shfl((int)csum, l1);
                    uint4 b0 = hv[l1 * 4], b1 = hv[l1 * 4 + 1], b2 = hv[l1 * 4 + 2], b3 = hv[l1 * 4 + 3];
                    uint32_t v[16] = {b0.x, b0.y, b0.z, b0.w, b1.x, b1.y, b1.z, b1.w,
                                      b2.x, b2.y, b2.z, b2.w, b3.x, b3.y, b3.z, b3.w};
                    uint32_t acc = carry2, bCnt = 0; int bin = l1 * 16;
                    #pragma unroll
                    for (int t = 15; t >= 0; --t) {
                        uint32_t cc = v[t];
                        if (acc + cc >= NEEDF) { bin = l1 * 16 + t; bCnt = cc; break; }
                        acc += cc;
                    }
                    uint32_t cntIncl = acc + bCnt;
                    if (lane == 0) {
                        if (cntIncl <= CAPF) { shr[1] = 0u; shr[0] = prefix | ((uint32_t)bin << shift); }
                        else { shr[1] = 1u; shr[2] = prefix | ((uint32_t)bin << shift); shr[3] = acc; }
                    }
                }
            } else {
                uint32_t v0 = sHist[0], v1 = sHist[1], v2 = sHist[2], v3 = sHist[3];
                uint32_t v[4] = {v0, v1, v2, v3};
                uint32_t acc = carry, bCnt = 0; int bin = 0;
                #pragma unroll
                for (int t = 3; t >= 0; --t) {
                    uint32_t cc = v[t];
                    if (acc + cc >= NEEDF) { bin = t; bCnt = cc; break; }
                    acc += cc;
                }
                uint32_t cntIncl = acc + bCnt;
                if (lane == 0) {
                    shr[1] = 0u;
                    if (cntIncl <= CAPF) shr[0] = prefix | (uint32_t)bin;
                    else shr[0] = (prefix | (uint32_t)bin) + 1u;   // exclude exact tie-key; continuation recovers
                }
            }
        }
        __syncthreads();
        if (shr[1] == 0u) { Tsel = shr[0]; break; }
        prefix = shr[2]; carry = shr[3];
    }
    __syncthreads();
    if (tid == 0) shr[3] = 0u;
    __syncthreads();

    // ---- phase 3: compact (packed u64: key<<32 | (0xFFFF - n) => order = pack desc)
    #pragma unroll
    for (int i = 0; i < NREG; ++i) {
        uint32_t k = rKey[i];
        if (k > THRBITS && k >= Tsel) {
            uint32_t s = atomicAdd(&shr[3], 1u);
            if (s < CAPF) cPack[s] = ((unsigned long long)k << 32) | (uint32_t)(0xFFFFu - (tid + i * TBS));
        }
    }
    __syncthreads();
    int cnt = (int)shr[3]; if (cnt > CAPF) cnt = CAPF;
    if (tid < 16) cPack[cnt + tid] = 0ull;
    __syncthreads();

    // ---- phase 4: rank-sort, 16 candidates per iteration (batched b128 reads)
    {
        bool h0 = tid < cnt;
        unsigned long long my = h0 ? cPack[tid] : 0ull;
        int r0 = 0;
        const ulonglong2* cp2 = (const ulonglong2*)cPack;
        int nb16 = (cnt + 15) >> 4;
        for (int jb = 0; jb < nb16; ++jb) {
            ulonglong2 p0 = cp2[jb * 8 + 0], p1 = cp2[jb * 8 + 1], p2 = cp2[jb * 8 + 2], p3 = cp2[jb * 8 + 3];
            ulonglong2 p4 = cp2[jb * 8 + 4], p5 = cp2[jb * 8 + 5], p6 = cp2[jb * 8 + 6], p7 = cp2[jb * 8 + 7];
            r0 += (p0.x > my) + (p0.y > my) + (p1.x > my) + (p1.y > my)
                + (p2.x > my) + (p2.y > my) + (p3.x > my) + (p3.y > my)
                + (p4.x > my) + (p4.y > my) + (p5.x > my) + (p5.y > my)
                + (p6.x > my) + (p6.y > my) + (p7.x > my) + (p7.y > my);
        }
        if (h0) {
            sKeyS[r0] = (uint32_t)(my >> 32);
            sIdxS[r0] = (uint16_t)(0xFFFFu - (uint32_t)(my & 0xFFFFu));
        }
        __syncthreads();
    }

    // ---- phase 5: gather + inline-decode candidate boxes
    if (tid < cnt) bBoxS[tid] = decode_one(sIdxS[tid], b, bb0, bb1, bb2);
    __syncthreads();

    // ---- phase 6: suppression bitmatrix — 1024 threads = 256 cands x 4 row-blocks, one tile each
    int lim = (cnt < MTX) ? cnt : MTX;
    {
        int cand = tid & 255, rb = tid >> 8;
        unsigned long long m = 0ull;
        if (cand < lim) {
            float4 bcx = bBoxS[cand];
            int j0 = rb << 6;
            #pragma unroll 8
            for (int jj = 0; jj < 64; ++jj)
                if (iou_gt(bBoxS[j0 + jj], bcx)) m |= 1ull << jj;   // rows >= cnt are garbage -> bits only affect inactive flags
        }
        colM[cand][rb] = m;
    }
    __syncthreads();

    // ---- phase 7: serial walk on wave 0 — ballot + register bit ops only
    float4 kb0 = make_float4(0.f, 0.f, 0.f, 0.f), kb1 = kb0;
    float ks0 = -1.0f, ks1 = -1.0f;
    int K = 0;
    if (tid < 64) {
        unsigned long long cA[4], cB[4], cC[4], cD[4];
        #pragma unroll
        for (int rb = 0; rb < 4; ++rb) {
            cA[rb] = colM[lane][rb];
            cB[rb] = colM[64 + lane][rb];
            cC[rb] = colM[128 + lane][rb];
            cD[rb] = colM[192 + lane][rb];
        }
        bool a0 = lane < lim, a1 = 64 + lane < lim, a2 = 128 + lane < lim, a3 = 192 + lane < lim;
        int kIA = -1, kIB = -1;
        while (K < KEEP) {
            unsigned long long m0 = __ballot(a0);
            unsigned long long m1 = __ballot(a1);
            unsigned long long m2 = __ballot(a2);
            unsigned long long m3 = __ballot(a3);
            int i;
            if (m0)      i = (int)__ffsll(m0) - 1;
            else if (m1) i = 64 + (int)__ffsll(m1) - 1;
            else if (m2) i = 128 + (int)__ffsll(m2) - 1;
            else if (m3) i = 192 + (int)__ffsll(m3) - 1;
            else break;
            int rb = i >> 6, il = i & 63;
            unsigned long long w0, w1, w2, w3;
            if (rb == 0)      { w0 = cA[0]; w1 = cB[0]; w2 = cC[0]; w3 = cD[0]; }
            else if (rb == 1) { w0 = cA[1]; w1 = cB[1]; w2 = cC[1]; w3 = cD[1]; }
            else if (rb == 2) { w0 = cA[2]; w1 = cB[2]; w2 = cC[2]; w3 = cD[2]; }
            else              { w0 = cA[3]; w1 = cB[3]; w2 = cC[3]; w3 = cD[3]; }
            if (rb == 0      && lane == il) a0 = false;
            else if (rb == 1 && lane == il) a1 = false;
            else if (rb == 2 && lane == il) a2 = false;
            else if (rb == 3 && lane == il) a3 = false;
            a0 = a0 && !((w0 >> il) & 1ull);
            a1 = a1 && !((w1 >> il) & 1ull);
            a2 = a2 && !((w2 >> il) & 1ull);
            a3 = a3 && !((w3 >> il) & 1ull);
            if (K < 64) { if (lane == K) kIA = i; }
            else        { if (lane == K - 64) kIB = i; }
            K++;
        }
        if (kIA >= 0) { kb0 = bBoxS[kIA]; ks0 = __uint_as_float(sKeyS[kIA]); }
        if (kIB >= 0) { kb1 = bBoxS[kIB]; ks1 = __uint_as_float(sKeyS[kIB]); }
        // mid-walk beyond matrix (cnt > MTX; rare)
        for (int i = lim; i < cnt && K < KEEP; ++i) {
            float4 bx = bBoxS[i];
            bool sup = false;
            if (lane < K)      sup = iou_gt(bx, kb0);
            if (64 + lane < K) sup = sup || iou_gt(bx, kb1);
            if (!__any(sup ? 1 : 0)) {
                float sc = __uint_as_float(sKeyS[i]);
                if (K < 64) { if (lane == K)      { kb0 = bx; ks0 = sc; } }
                else        { if (lane == K - 64) { kb1 = bx; ks1 = sc; } }
                K++;
            }
        }
        if (lane == 0) {
            shr[0] = (uint32_t)K;
            shr[1] = (uint32_t)cnt;
            shr[2] = (cnt > 0) ? sKeyS[cnt - 1] : 0xFFFFFFFFu;
            shr[3] = (cnt > 0) ? (uint32_t)sIdxS[cnt - 1] : 0xFFFFFFFFu;
        }
    }
    __syncthreads();
    int Kall = (int)shr[0]; int e = (int)shr[1];
    uint32_t cK = shr[2], cI = shr[3];

    // ---- phase 8: exact continuation via block argmax (rare)
    if (Kall < KEEP && e < PRETOPK) {
        for (;;) {
            if (tid == 0) sh64 = 0ull;
            __syncthreads();
            unsigned long long best = 0ull;
            #pragma unroll
            for (int i = 0; i < NREG; ++i) {
                uint32_t k = rKey[i]; int n = tid + i * TBS;
                if (k > THRBITS && (k < cK || (k == cK && (uint32_t)n > cI))) {
                    unsigned long long v = ((unsigned long long)k << 32) | (unsigned long long)(NPTS - 1 - n);
                    if (v > best) best = v;
                }
            }
            if (best) atomicMax(&sh64, best);
            __syncthreads();
            unsigned long long bv = sh64;
            if (bv == 0ull) break;
            uint32_t k = (uint32_t)(bv >> 32);
            int n = NPTS - 1 - (int)(bv & 0xFFFFFFFFull);
            if (tid < 64) {
                float4 bx = decode_one(n, b, bb0, bb1, bb2);
                bool sup = false;
                if (lane < K)      sup = iou_gt(bx, kb0);
                if (64 + lane < K) sup = sup || iou_gt(bx, kb1);
                if (!__any(sup ? 1 : 0)) {
                    float sc = __uint_as_float(k);
                    if (K < 64) { if (lane == K)      { kb0 = bx; ks0 = sc; } }
                    else        { if (lane == K - 64) { kb1 = bx; ks1 = sc; } }
                    K++;
                }
                if (lane == 0) shr[0] = (uint32_t)K;
            }
            __syncthreads();
            Kall = (int)shr[0];
            e++; cK = k; cI = (uint32_t)n;
            if (Kall >= KEEP || e >= PRETOPK) break;
        }
    }

    // ---- write per-class results
    if (tid < 64) {
        int off = (b * NCLS + c) * KEEP;
        float4 z = make_float4(0.f, 0.f, 0.f, 0.f);
        keptScore[off + lane] = (lane < K) ? ks0 : -1.0f;
        keptBox[off + lane]   = (lane < K) ? kb0 : z;
        if (64 + lane < KEEP) {
            keptScore[off + 64 + lane] = (64 + lane < K) ? ks1 : -1.0f;
            keptBox[off + 64 + lane]   = (64 + lane < K) ? kb1 : z;
        }
    }
}

// ---------------------------------------------------------------- topk (unchanged from R10)
__device__ void scan_cross_fast(const uint32_t* hist, int nb, uint32_t need, uint32_t cap,
                                uint32_t carry, uint32_t prefix, int shift, int level,
                                uint32_t* shr, int lane) {
    uint32_t csum;
    if (nb == 4096) {
        uint32_t s = 0;
        int cb = lane << 6;
        #pragma unroll 8
        for (int i = 0; i < 64; ++i) s += hist[cb + i];
        csum = s;
    } else {
        csum = hist[lane];
    }
    uint32_t suf = csum;
    #pragma unroll
    for (int d = 1; d < 64; d <<= 1) {
        uint32_t t = (uint32_t)__shfl_down((int)suf, d);
        if (lane + d < 64) suf += t;
    }
    unsigned long long m = __ballot(carry + suf >= need);
    if (!m) { if (lane == 0) { shr[1] = 0u; shr[0] = 0u; } return; }
    int l1 = 63 - __clzll(m);
    uint32_t sufL1 = (uint32_t)__shfl((int)suf, l1);
    uint32_t csumL1 = (uint32_t)__shfl((int)csum, l1);
    uint32_t carry2 = carry + sufL1 - csumL1;
    int foundBin; uint32_t cAbove, bCnt;
    if (nb == 4096) {
        int cb = l1 << 6;
        uint32_t c2 = hist[cb + lane];
        uint32_t suf2 = c2;
        #pragma unroll
        for (int d = 1; d < 64; d <<= 1) {
            uint32_t t = (uint32_t)__shfl_down((int)suf2, d);
            if (lane + d < 64) suf2 += t;
        }
        unsigned long long m2 = __ballot(carry2 + suf2 >= need);
        int l2 = 63 - __clzll(m2);
        foundBin = cb + l2;
        uint32_t suf2L = (uint32_t)__shfl((int)suf2, l2);
        uint32_t c2L = (uint32_t)__shfl((int)c2, l2);
        cAbove = carry2 + suf2L - c2L;
        bCnt = c2L;
    } else {
        foundBin = l1; cAbove = carry2; bCnt = csumL1;
    }
    if (lane == 0) {
        uint32_t cntIncl = cAbove + bCnt;
        if (cntIncl <= cap) { shr[1] = 0u; shr[0] = prefix | ((uint32_t)foundBin << shift); }
        else if (level == 2) { shr[1] = 0u; shr[0] = (prefix | (uint32_t)foundBin) + 1u; }
        else { shr[1] = 1u; shr[2] = prefix | ((uint32_t)foundBin << shift); shr[3] = cAbove; }
    }
}

__global__ __launch_bounds__(TBT)
void topk_out(const float* __restrict__ keptScore, const float4* __restrict__ keptBox,
              float* __restrict__ out) {
    __shared__ uint32_t sHist[4096];
    __shared__ __align__(16) unsigned long long cPackT[CAPT + 16];
    __shared__ uint32_t sKeyS[CAPT];
    __shared__ uint16_t sIdxS[CAPT];
    __shared__ uint32_t shr[4];
    int b = blockIdx.x, tid = threadIdx.x, lane = tid & 63;
    const int TOT = NCLS * KEEP;

    uint32_t rKey[NREGT];
    #pragma unroll
    for (int i = 0; i < NREGT; ++i) {
        int n = tid + i * TBT;
        uint32_t key = 0u;
        if (n < TOT) {
            float s = keptScore[b * TOT + n];
            key = (s > 0.f) ? __float_as_uint(s) : 0u;
        }
        rKey[i] = key;
    }

    uint32_t prefix = 0, carry = 0, Tsel = 0;
    for (int level = 0;; ++level) {
        int shift = (level == 0) ? 18 : (level == 1 ? 6 : 0);
        int nb = (level == 2) ? 64 : 4096;
        __syncthreads();
        for (int i = tid; i < nb; i += TBT) sHist[i] = 0;
        __syncthreads();
        #pragma unroll
        for (int i = 0; i < NREGT; ++i) {
            uint32_t k = rKey[i];
            if (k > 0u) {
                if (level == 0) atomicAdd(&sHist[k >> 18], 1u);
                else if (level == 1) { if ((k >> 18) == (prefix >> 18)) atomicAdd(&sHist[(k >> 6) & 0xFFFu], 1u); }
                else { if ((k >> 6) == (prefix >> 6)) atomicAdd(&sHist[k & 0x3Fu], 1u); }
            }
        }
        __syncthreads();
        if (tid < 64) scan_cross_fast(sHist, nb, (uint32_t)KEEP, CAPT, carry, prefix, shift, level, shr, lane);
        __syncthreads();
        if (shr[1] == 0u) { Tsel = shr[0]; break; }
        prefix = shr[2]; carry = shr[3];
    }
    __syncthreads();
    if (tid == 0) shr[3] = 0u;
    __syncthreads();
    #pragma unroll
    for (int i = 0; i < NREGT; ++i) {
        uint32_t k = rKey[i];
        if (k > 0u && k >= Tsel) {
            uint32_t s = atomicAdd(&shr[3], 1u);
            if (s < CAPT) cPackT[s] = ((unsigned long long)k << 32) | (uint32_t)(0xFFFFu - (tid + i * TBT));
        }
    }
    __syncthreads();
    int cnt = (int)shr[3]; if (cnt > CAPT) cnt = CAPT;
    if (tid < 16) cPackT[cnt + tid] = 0ull;
    __syncthreads();

    {
        bool h0 = tid < cnt;
        unsigned long long my = h0 ? cPackT[tid] : 0ull;
        int r0 = 0;
        const ulonglong2* cp2 = (const ulonglong2*)cPackT;
        int nb16 = (cnt + 15) >> 4;
        for (int jb = 0; jb < nb16; ++jb) {
            ulonglong2 p0 = cp2[jb * 8 + 0], p1 = cp2[jb * 8 + 1], p2 = cp2[jb * 8 + 2], p3 = cp2[jb * 8 + 3];
            ulonglong2 p4 = cp2[jb * 8 + 4], p5 = cp2[jb * 8 + 5], p6 = cp2[jb * 8 + 6], p7 = cp2[jb * 8 + 7];
            r0 += (p0.x > my) + (p0.y > my) + (p1.x > my) + (p1.y > my)
                + (p2.x > my) + (p2.y > my) + (p3.x > my) + (p3.y > my)
                + (p4.x > my) + (p4.y > my) + (p5.x > my) + (p5.y > my)
                + (p6.x > my) + (p6.y > my) + (p7.x > my) + (p7.y > my);
        }
        if (h0) {
            sKeyS[r0] = (uint32_t)(my >> 32);
            sIdxS[r0] = (uint16_t)(0xFFFFu - (uint32_t)(my & 0xFFFFu));
        }
        __syncthreads();
    }

    if (tid < KEEP) {
        bool valid = tid < cnt;
        int fi = valid ? (int)sIdxS[tid] : 0;
        float sc = valid ? __uint_as_float(sKeyS[tid]) : 0.f;
        float4 bx = valid ? keptBox[b * TOT + fi] : make_float4(0.f, 0.f, 0.f, 0.f);
        float cls = valid ? (float)(fi / KEEP) : -1.0f;
        float* boxOut = out + NB + (b * KEEP + tid) * 4;
        boxOut[0] = bx.x; boxOut[1] = bx.y; boxOut[2] = bx.z; boxOut[3] = bx.w;
        out[NB + NB * KEEP * 4 + b * KEEP + tid] = sc;
        out[NB + NB * KEEP * 4 + NB * KEEP + b * KEEP + tid] = cls;
    }
    if (tid == 0) out[b] = (float)((cnt < KEEP) ? cnt : KEEP);
}

// ---------------------------------------------------------------- launch
extern "C" void kernel_launch(void* const* d_in, const int* in_sizes, int n_in,
                              void* d_out, int out_size, void* d_ws, size_t ws_size,
                              hipStream_t stream) {
    const float* cls0 = (const float*)d_in[0];
    const float* bb0  = (const float*)d_in[1];
    const float* obj0 = (const float*)d_in[2];
    const float* cls1 = (const float*)d_in[3];
    const float* bb1  = (const float*)d_in[4];
    const float* obj1 = (const float*)d_in[5];
    const float* cls2 = (const float*)d_in[6];
    const float* bb2  = (const float*)d_in[7];
    const float* obj2 = (const float*)d_in[8];
    float* out = (float*)d_out;

    char* ws = (char*)d_ws;
    float*  keptScore = (float*)(ws);                  //   256,000 B
    float4* keptBox   = (float4*)(ws + 256000);        // 1,024,000 B

    select_nms<<<NB * NCLS, TBS, 0, stream>>>(cls0, bb0, obj0, cls1, bb1, obj1,
                                              cls2, bb2, obj2, keptScore, keptBox);
    topk_out<<<NB, TBT, 0, stream>>>(keptScore, keptBox, out);
}

// Round 12
// 183.153 us; speedup vs baseline: 1.8647x; 1.1524x over previous
//
#include <hip/hip_runtime.h>
#include <math.h>
#include <stdint.h>

#define NCLS   80
#define NPTS   8400
#define KEEP   100
#define PRETOPK 5000
#define NB     8
#define THRBITS 0x3C23D70Au   // bits of 0.01f (scores positive floats -> int-ordered)

#define TBS    1024           // select block size
#define CAPF   512            // candidate cap
#define NEEDF  192u           // selection target
#define MTX    256            // suppression-matrix size
#define NW4    2100           // NPTS / 4 (uint4 words)

#define TBT    1024           // topk block size
#define NREGT  8              // 8000/1024
#define CAPT   512

__device__ __forceinline__ float sigmoidf_(float x) { return 1.0f / (1.0f + expf(-x)); }

__device__ __forceinline__ uint32_t score_key(int n, int b, int c,
        const float* cls0, const float* obj0, const float* cls1, const float* obj1,
        const float* cls2, const float* obj2) {
    const float *clsP, *objP; int base, HW;
    if (n < 6400)      { clsP = cls0; objP = obj0; base = n;        HW = 6400; }
    else if (n < 8000) { clsP = cls1; objP = obj1; base = n - 6400; HW = 1600; }
    else               { clsP = cls2; objP = obj2; base = n - 8000; HW = 400;  }
    float cv = clsP[((size_t)b * NCLS + c) * HW + base];
    float ov = objP[(size_t)b * HW + base];
    return __float_as_uint(sigmoidf_(cv) * sigmoidf_(ov));
}

__device__ __forceinline__ float4 decode_one(int n, int b,
        const float* bb0, const float* bb1, const float* bb2) {
    const float* bb; int base, HW, x, y; float s;
    if (n < 6400)      { bb = bb0; base = n;        HW = 6400; s = 8.f;  y = base / 80; x = base - y * 80; }
    else if (n < 8000) { bb = bb1; base = n - 6400; HW = 1600; s = 16.f; y = base / 40; x = base - y * 40; }
    else               { bb = bb2; base = n - 8000; HW = 400;  s = 32.f; y = base / 20; x = base - y * 20; }
    const float* p = bb + (size_t)b * 4 * HW + base;
    float v0 = p[0], v1 = p[HW], v2 = p[2 * HW], v3 = p[3 * HW];
    float cx = v0 * s + x * s, cy = v1 * s + y * s;
    float w = expf(v2) * s, h = expf(v3) * s;
    return make_float4(cx - 0.5f * w, cy - 0.5f * h, cx + 0.5f * w, cy + 0.5f * h);
}

__device__ __forceinline__ bool iou_gt(float4 a, float4 c) {
    float tlx = fmaxf(a.x, c.x), tly = fmaxf(a.y, c.y);
    float brx = fminf(a.z, c.z), bry = fminf(a.w, c.w);
    float w = fmaxf(brx - tlx, 0.f), h = fmaxf(bry - tly, 0.f);
    float inter = w * h;
    float a1 = (a.z - a.x) * (a.w - a.y);
    float a2 = (c.z - c.x) * (c.w - c.y);
    return inter / (a1 + a2 - inter + 1e-6f) > 0.65f;
}

// ================================================================ fused per-(b,c) select + sort + NMS
// Keys live in LDS (sKey) — NO per-thread key arrays, no scratch spills.
__global__ __launch_bounds__(TBS, 8)
void select_nms(const float* __restrict__ cls0, const float* __restrict__ bb0, const float* __restrict__ obj0,
                const float* __restrict__ cls1, const float* __restrict__ bb1, const float* __restrict__ obj1,
                const float* __restrict__ cls2, const float* __restrict__ bb2, const float* __restrict__ obj2,
                float* __restrict__ keptScore, float4* __restrict__ keptBox) {
    __shared__ __align__(16) uint32_t sKey[NPTS];                // 33.6 KB
    __shared__ uint32_t sHist[1024];                             // 4 KB
    __shared__ __align__(16) unsigned long long cPack[CAPF + 16];// 4.2 KB
    __shared__ uint32_t sKeyS[CAPF];                             // 2 KB
    __shared__ uint16_t sIdxS[CAPF];                             // 1 KB
    __shared__ float4   bBoxS[CAPF];                             // 8 KB
    __shared__ __align__(16) unsigned long long colM[MTX][4];    // 8 KB
    __shared__ uint32_t shr[4];
    __shared__ unsigned long long sh64;

    int bc = blockIdx.x;
    int b = bc & 7;                  // XCD-locality: image b -> XCD b
    int c = bc >> 3;
    int tid = threadIdx.x, lane = tid & 63;

    // ---- phase 1: keygen -> LDS, fused with level-0 histogram
    sHist[tid] = 0;
    __syncthreads();
    for (int i = 0; i < 9; ++i) {
        int n = tid + i * TBS;
        if (n < NPTS) {
            uint32_t k = score_key(n, b, c, cls0, obj0, cls1, obj1, cls2, obj2);
            sKey[n] = k;
            if (k > THRBITS) atomicAdd(&sHist[k >> 22], 1u);
        }
    }
    __syncthreads();

    // ---- phase 2: exact radix threshold selection (levels 10/10/10/2 bits)
    uint32_t prefix = 0, carry = 0, Tsel = 0;
    const uint4* k4 = (const uint4*)sKey;
    for (int level = 0;; ++level) {
        int shift = (level == 0) ? 22 : (level == 1) ? 12 : (level == 2) ? 2 : 0;
        bool nb4 = (level == 3);
        // hist for this level is ready here; scan it
        if (tid < 64) {
            if (!nb4) {
                const uint4* hv = (const uint4*)sHist;
                uint4 q0 = hv[lane * 4], q1 = hv[lane * 4 + 1], q2 = hv[lane * 4 + 2], q3 = hv[lane * 4 + 3];
                uint32_t csum = q0.x + q0.y + q0.z + q0.w + q1.x + q1.y + q1.z + q1.w
                              + q2.x + q2.y + q2.z + q2.w + q3.x + q3.y + q3.z + q3.w;
                uint32_t suf = csum;
                #pragma unroll
                for (int d = 1; d < 64; d <<= 1) {
                    uint32_t t = (uint32_t)__shfl_down((int)suf, d);
                    if (lane + d < 64) suf += t;
                }
                unsigned long long m = __ballot(carry + suf >= NEEDF);
                if (!m) { if (lane == 0) { shr[1] = 0u; shr[0] = 0u; } }
                else {
                    int l1 = 63 - __clzll(m);
                    uint32_t carry2 = carry + (uint32_t)__shfl((int)suf, l1) - (uint32_t)__shfl((int)csum, l1);
                    uint4 b0 = hv[l1 * 4], b1 = hv[l1 * 4 + 1], b2 = hv[l1 * 4 + 2], b3 = hv[l1 * 4 + 3];
                    uint32_t v[16] = {b0.x, b0.y, b0.z, b0.w, b1.x, b1.y, b1.z, b1.w,
                                      b2.x, b2.y, b2.z, b2.w, b3.x, b3.y, b3.z, b3.w};
                    uint32_t acc = carry2, bCnt = 0; int bin = l1 * 16;
                    #pragma unroll
                    for (int t = 15; t >= 0; --t) {
                        uint32_t cc = v[t];
                        if (acc + cc >= NEEDF) { bin = l1 * 16 + t; bCnt = cc; break; }
                        acc += cc;
                    }
                    uint32_t cntIncl = acc + bCnt;
                    if (lane == 0) {
                        if (cntIncl <= CAPF) { shr[1] = 0u; shr[0] = prefix | ((uint32_t)bin << shift); }
                        else { shr[1] = 1u; shr[2] = prefix | ((uint32_t)bin << shift); shr[3] = acc; }
                    }
                }
            } else {
                uint32_t v0 = sHist[0], v1 = sHist[1], v2 = sHist[2], v3 = sHist[3];
                uint32_t v[4] = {v0, v1, v2, v3};
                uint32_t acc = carry, bCnt = 0; int bin = 0;
                #pragma unroll
                for (int t = 3; t >= 0; --t) {
                    uint32_t cc = v[t];
                    if (acc + cc >= NEEDF) { bin = t; bCnt = cc; break; }
                    acc += cc;
                }
                uint32_t cntIncl = acc + bCnt;
                if (lane == 0) {
                    shr[1] = 0u;
                    if (cntIncl <= CAPF) shr[0] = prefix | (uint32_t)bin;
                    else shr[0] = (prefix | (uint32_t)bin) + 1u;   // exclude exact tie-key; continuation recovers
                }
            }
        }
        __syncthreads();
        if (shr[1] == 0u) { Tsel = shr[0]; break; }
        prefix = shr[2]; carry = shr[3];
        // build next level's histogram from LDS keys
        int nl = level + 1;
        if (nl == 3) { if (tid < 4) sHist[tid] = 0; } else sHist[tid] = 0;
        __syncthreads();
        for (int i = 0; i < 3; ++i) {
            int w = tid + i * 1024;
            if (w < NW4) {
                uint4 q = k4[w];
                uint32_t ks[4] = {q.x, q.y, q.z, q.w};
                #pragma unroll
                for (int j = 0; j < 4; ++j) {
                    uint32_t k = ks[j];
                    if (k > THRBITS) {
                        if (nl == 1) { if ((k >> 22) == (prefix >> 22)) atomicAdd(&sHist[(k >> 12) & 1023u], 1u); }
                        else if (nl == 2) { if ((k >> 12) == (prefix >> 12)) atomicAdd(&sHist[(k >> 2) & 1023u], 1u); }
                        else { if ((k >> 2) == (prefix >> 2)) atomicAdd(&sHist[k & 3u], 1u); }
                    }
                }
            }
        }
        __syncthreads();
    }
    __syncthreads();
    if (tid == 0) shr[3] = 0u;
    __syncthreads();

    // ---- phase 3: compact from LDS keys (packed u64: key<<32 | (0xFFFF - n))
    for (int i = 0; i < 3; ++i) {
        int w = tid + i * 1024;
        if (w < NW4) {
            uint4 q = k4[w];
            uint32_t ks[4] = {q.x, q.y, q.z, q.w};
            #pragma unroll
            for (int j = 0; j < 4; ++j) {
                uint32_t k = ks[j];
                if (k > THRBITS && k >= Tsel) {
                    uint32_t s = atomicAdd(&shr[3], 1u);
                    int n = w * 4 + j;
                    if (s < CAPF) cPack[s] = ((unsigned long long)k << 32) | (uint32_t)(0xFFFFu - n);
                }
            }
        }
    }
    __syncthreads();
    int cnt = (int)shr[3]; if (cnt > CAPF) cnt = CAPF;
    if (tid < 16) cPack[cnt + tid] = 0ull;
    __syncthreads();

    // ---- phase 4: rank-sort, 16 candidates per iteration (batched b128 reads)
    {
        bool h0 = tid < cnt;
        unsigned long long my = h0 ? cPack[tid] : 0ull;
        int r0 = 0;
        const ulonglong2* cp2 = (const ulonglong2*)cPack;
        int nb16 = (cnt + 15) >> 4;
        for (int jb = 0; jb < nb16; ++jb) {
            ulonglong2 p0 = cp2[jb * 8 + 0], p1 = cp2[jb * 8 + 1], p2 = cp2[jb * 8 + 2], p3 = cp2[jb * 8 + 3];
            ulonglong2 p4 = cp2[jb * 8 + 4], p5 = cp2[jb * 8 + 5], p6 = cp2[jb * 8 + 6], p7 = cp2[jb * 8 + 7];
            r0 += (p0.x > my) + (p0.y > my) + (p1.x > my) + (p1.y > my)
                + (p2.x > my) + (p2.y > my) + (p3.x > my) + (p3.y > my)
                + (p4.x > my) + (p4.y > my) + (p5.x > my) + (p5.y > my)
                + (p6.x > my) + (p6.y > my) + (p7.x > my) + (p7.y > my);
        }
        if (h0) {
            sKeyS[r0] = (uint32_t)(my >> 32);
            sIdxS[r0] = (uint16_t)(0xFFFFu - (uint32_t)(my & 0xFFFFu));
        }
        __syncthreads();
    }

    // ---- phase 5: gather + inline-decode candidate boxes
    if (tid < cnt) bBoxS[tid] = decode_one(sIdxS[tid], b, bb0, bb1, bb2);
    __syncthreads();

    // ---- phase 6: suppression bitmatrix (IoU symmetric -> row==col semantics)
    int lim = (cnt < MTX) ? cnt : MTX;
    {
        int cand = tid & 255, rb = tid >> 8;
        unsigned long long m = 0ull;
        if (cand < lim) {
            float4 bcx = bBoxS[cand];
            int j0 = rb << 6;
            #pragma unroll 8
            for (int jj = 0; jj < 64; ++jj)
                if (iou_gt(bBoxS[j0 + jj], bcx)) m |= 1ull << jj;
        }
        colM[cand][rb] = m;
    }
    __syncthreads();

    // ---- phase 7: serial walk on wave 0 — ffs-jump, rows from LDS (broadcast b128)
    float4 kb0 = make_float4(0.f, 0.f, 0.f, 0.f), kb1 = kb0;
    float ks0 = -1.0f, ks1 = -1.0f;
    int K = 0;
    if (tid < 64) {
        unsigned long long U0, U1, U2, U3;
        U0 = (lim >= 64) ? ~0ull : ((lim > 0) ? ((1ull << lim) - 1) : 0ull);
        U1 = (lim >= 128) ? ~0ull : ((lim > 64) ? ((1ull << (lim - 64)) - 1) : 0ull);
        U2 = (lim >= 192) ? ~0ull : ((lim > 128) ? ((1ull << (lim - 128)) - 1) : 0ull);
        U3 = (lim >= 256) ? ~0ull : ((lim > 192) ? ((1ull << (lim - 192)) - 1) : 0ull);
        int kIA = -1, kIB = -1;
        while (K < KEEP) {
            int i;
            if (U0) i = (int)__ffsll(U0) - 1;
            else if (U1) i = 64 + (int)__ffsll(U1) - 1;
            else if (U2) i = 128 + (int)__ffsll(U2) - 1;
            else if (U3) i = 192 + (int)__ffsll(U3) - 1;
            else break;
            ulonglong2 r01 = *(const ulonglong2*)&colM[i][0];   // broadcast
            ulonglong2 r23 = *(const ulonglong2*)&colM[i][2];
            if (i < 64)       U0 &= ~(1ull << i);
            else if (i < 128) U1 &= ~(1ull << (i - 64));
            else if (i < 192) U2 &= ~(1ull << (i - 128));
            else              U3 &= ~(1ull << (i - 192));
            U0 &= ~r01.x; U1 &= ~r01.y; U2 &= ~r23.x; U3 &= ~r23.y;
            if (K < 64) { if (lane == K) kIA = i; }
            else        { if (lane == K - 64) kIB = i; }
            K++;
        }
        if (kIA >= 0) { kb0 = bBoxS[kIA]; ks0 = __uint_as_float(sKeyS[kIA]); }
        if (kIB >= 0) { kb1 = bBoxS[kIB]; ks1 = __uint_as_float(sKeyS[kIB]); }
        // mid-walk beyond matrix (cnt > MTX; rare)
        for (int i = lim; i < cnt && K < KEEP; ++i) {
            float4 bx = bBoxS[i];
            bool sup = false;
            if (lane < K)      sup = iou_gt(bx, kb0);
            if (64 + lane < K) sup = sup || iou_gt(bx, kb1);
            if (!__any(sup ? 1 : 0)) {
                float sc = __uint_as_float(sKeyS[i]);
                if (K < 64) { if (lane == K)      { kb0 = bx; ks0 = sc; } }
                else        { if (lane == K - 64) { kb1 = bx; ks1 = sc; } }
                K++;
            }
        }
        if (lane == 0) {
            shr[0] = (uint32_t)K;
            shr[1] = (uint32_t)cnt;
            shr[2] = (cnt > 0) ? sKeyS[cnt - 1] : 0xFFFFFFFFu;
            shr[3] = (cnt > 0) ? (uint32_t)sIdxS[cnt - 1] : 0xFFFFFFFFu;
        }
    }
    __syncthreads();
    int Kall = (int)shr[0]; int e = (int)shr[1];
    uint32_t cK = shr[2], cI = shr[3];

    // ---- phase 8: exact continuation via block argmax over LDS keys (rare)
    if (Kall < KEEP && e < PRETOPK) {
        for (;;) {
            if (tid == 0) sh64 = 0ull;
            __syncthreads();
            unsigned long long best = 0ull;
            for (int i = 0; i < 9; ++i) {
                int n = tid + i * TBS;
                if (n < NPTS) {
                    uint32_t k = sKey[n];
                    if (k > THRBITS && (k < cK || (k == cK && (uint32_t)n > cI))) {
                        unsigned long long v = ((unsigned long long)k << 32) | (unsigned long long)(NPTS - 1 - n);
                        if (v > best) best = v;
                    }
                }
            }
            if (best) atomicMax(&sh64, best);
            __syncthreads();
            unsigned long long bv = sh64;
            if (bv == 0ull) break;
            uint32_t k = (uint32_t)(bv >> 32);
            int n = NPTS - 1 - (int)(bv & 0xFFFFFFFFull);
            if (tid < 64) {
                float4 bx = decode_one(n, b, bb0, bb1, bb2);
                bool sup = false;
                if (lane < K)      sup = iou_gt(bx, kb0);
                if (64 + lane < K) sup = sup || iou_gt(bx, kb1);
                if (!__any(sup ? 1 : 0)) {
                    float sc = __uint_as_float(k);
                    if (K < 64) { if (lane == K)      { kb0 = bx; ks0 = sc; } }
                    else        { if (lane == K - 64) { kb1 = bx; ks1 = sc; } }
                    K++;
                }
                if (lane == 0) shr[0] = (uint32_t)K;
            }
            __syncthreads();
            Kall = (int)shr[0];
            e++; cK = k; cI = (uint32_t)n;
            if (Kall >= KEEP || e >= PRETOPK) break;
        }
    }

    // ---- write per-class results
    if (tid < 64) {
        int off = (b * NCLS + c) * KEEP;
        float4 z = make_float4(0.f, 0.f, 0.f, 0.f);
        keptScore[off + lane] = (lane < K) ? ks0 : -1.0f;
        keptBox[off + lane]   = (lane < K) ? kb0 : z;
        if (64 + lane < KEEP) {
            keptScore[off + 64 + lane] = (64 + lane < K) ? ks1 : -1.0f;
            keptBox[off + 64 + lane]   = (64 + lane < K) ? kb1 : z;
        }
    }
}

// ---------------------------------------------------------------- topk (unchanged from R11)
__device__ void scan_cross_fast(const uint32_t* hist, int nb, uint32_t need, uint32_t cap,
                                uint32_t carry, uint32_t prefix, int shift, int level,
                                uint32_t* shr, int lane) {
    uint32_t csum;
    if (nb == 4096) {
        uint32_t s = 0;
        int cb = lane << 6;
        #pragma unroll 8
        for (int i = 0; i < 64; ++i) s += hist[cb + i];
        csum = s;
    } else {
        csum = hist[lane];
    }
    uint32_t suf = csum;
    #pragma unroll
    for (int d = 1; d < 64; d <<= 1) {
        uint32_t t = (uint32_t)__shfl_down((int)suf, d);
        if (lane + d < 64) suf += t;
    }
    unsigned long long m = __ballot(carry + suf >= need);
    if (!m) { if (lane == 0) { shr[1] = 0u; shr[0] = 0u; } return; }
    int l1 = 63 - __clzll(m);
    uint32_t sufL1 = (uint32_t)__shfl((int)suf, l1);
    uint32_t csumL1 = (uint32_t)__shfl((int)csum, l1);
    uint32_t carry2 = carry + sufL1 - csumL1;
    int foundBin; uint32_t cAbove, bCnt;
    if (nb == 4096) {
        int cb = l1 << 6;
        uint32_t c2 = hist[cb + lane];
        uint32_t suf2 = c2;
        #pragma unroll
        for (int d = 1; d < 64; d <<= 1) {
            uint32_t t = (uint32_t)__shfl_down((int)suf2, d);
            if (lane + d < 64) suf2 += t;
        }
        unsigned long long m2 = __ballot(carry2 + suf2 >= need);
        int l2 = 63 - __clzll(m2);
        foundBin = cb + l2;
        uint32_t suf2L = (uint32_t)__shfl((int)suf2, l2);
        uint32_t c2L = (uint32_t)__shfl((int)c2, l2);
        cAbove = carry2 + suf2L - c2L;
        bCnt = c2L;
    } else {
        foundBin = l1; cAbove = carry2; bCnt = csumL1;
    }
    if (lane == 0) {
        uint32_t cntIncl = cAbove + bCnt;
        if (cntIncl <= cap) { shr[1] = 0u; shr[0] = prefix | ((uint32_t)foundBin << shift); }
        else if (level == 2) { shr[1] = 0u; shr[0] = (prefix | (uint32_t)foundBin) + 1u; }
        else { shr[1] = 1u; shr[2] = prefix | ((uint32_t)foundBin << shift); shr[3] = cAbove; }
    }
}

__global__ __launch_bounds__(TBT)
void topk_out(const float* __restrict__ keptScore, const float4* __restrict__ keptBox,
              float* __restrict__ out) {
    __shared__ uint32_t sHist[4096];
    __shared__ __align__(16) unsigned long long cPackT[CAPT + 16];
    __shared__ uint32_t sKeyS[CAPT];
    __shared__ uint16_t sIdxS[CAPT];
    __shared__ uint32_t shr[4];
    int b = blockIdx.x, tid = threadIdx.x, lane = tid & 63;
    const int TOT = NCLS * KEEP;

    uint32_t rKey[NREGT];
    #pragma unroll
    for (int i = 0; i < NREGT; ++i) {
        int n = tid + i * TBT;
        uint32_t key = 0u;
        if (n < TOT) {
            float s = keptScore[b * TOT + n];
            key = (s > 0.f) ? __float_as_uint(s) : 0u;
        }
        rKey[i] = key;
    }

    uint32_t prefix = 0, carry = 0, Tsel = 0;
    for (int level = 0;; ++level) {
        int shift = (level == 0) ? 18 : (level == 1 ? 6 : 0);
        int nb = (level == 2) ? 64 : 4096;
        __syncthreads();
        for (int i = tid; i < nb; i += TBT) sHist[i] = 0;
        __syncthreads();
        #pragma unroll
        for (int i = 0; i < NREGT; ++i) {
            uint32_t k = rKey[i];
            if (k > 0u) {
                if (level == 0) atomicAdd(&sHist[k >> 18], 1u);
                else if (level == 1) { if ((k >> 18) == (prefix >> 18)) atomicAdd(&sHist[(k >> 6) & 0xFFFu], 1u); }
                else { if ((k >> 6) == (prefix >> 6)) atomicAdd(&sHist[k & 0x3Fu], 1u); }
            }
        }
        __syncthreads();
        if (tid < 64) scan_cross_fast(sHist, nb, (uint32_t)KEEP, CAPT, carry, prefix, shift, level, shr, lane);
        __syncthreads();
        if (shr[1] == 0u) { Tsel = shr[0]; break; }
        prefix = shr[2]; carry = shr[3];
    }
    __syncthreads();
    if (tid == 0) shr[3] = 0u;
    __syncthreads();
    #pragma unroll
    for (int i = 0; i < NREGT; ++i) {
        uint32_t k = rKey[i];
        if (k > 0u && k >= Tsel) {
            uint32_t s = atomicAdd(&shr[3], 1u);
            if (s < CAPT) cPackT[s] = ((unsigned long long)k << 32) | (uint32_t)(0xFFFFu - (tid + i * TBT));
        }
    }
    __syncthreads();
    int cnt = (int)shr[3]; if (cnt > CAPT) cnt = CAPT;
    if (tid < 16) cPackT[cnt + tid] = 0ull;
    __syncthreads();

    {
        bool h0 = tid < cnt;
        unsigned long long my = h0 ? cPackT[tid] : 0ull;
        int r0 = 0;
        const ulonglong2* cp2 = (const ulonglong2*)cPackT;
        int nb16 = (cnt + 15) >> 4;
        for (int jb = 0; jb < nb16; ++jb) {
            ulonglong2 p0 = cp2[jb * 8 + 0], p1 = cp2[jb * 8 + 1], p2 = cp2[jb * 8 + 2], p3 = cp2[jb * 8 + 3];
            ulonglong2 p4 = cp2[jb * 8 + 4], p5 = cp2[jb * 8 + 5], p6 = cp2[jb * 8 + 6], p7 = cp2[jb * 8 + 7];
            r0 += (p0.x > my) + (p0.y > my) + (p1.x > my) + (p1.y > my)
                + (p2.x > my) + (p2.y > my) + (p3.x > my) + (p3.y > my)
                + (p4.x > my) + (p4.y > my) + (p5.x > my) + (p5.y > my)
                + (p6.x > my) + (p6.y > my) + (p7.x > my) + (p7.y > my);
        }
        if (h0) {
            sKeyS[r0] = (uint32_t)(my >> 32);
            sIdxS[r0] = (uint16_t)(0xFFFFu - (uint32_t)(my & 0xFFFFu));
        }
        __syncthreads();
    }

    if (tid < KEEP) {
        bool valid = tid < cnt;
        int fi = valid ? (int)sIdxS[tid] : 0;
        float sc = valid ? __uint_as_float(sKeyS[tid]) : 0.f;
        float4 bx = valid ? keptBox[b * TOT + fi] : make_float4(0.f, 0.f, 0.f, 0.f);
        float cls = valid ? (float)(fi / KEEP) : -1.0f;
        float* boxOut = out + NB + (b * KEEP + tid) * 4;
        boxOut[0] = bx.x; boxOut[1] = bx.y; boxOut[2] = bx.z; boxOut[3] = bx.w;
        out[NB + NB * KEEP * 4 + b * KEEP + tid] = sc;
        out[NB + NB * KEEP * 4 + NB * KEEP + b * KEEP + tid] = cls;
    }
    if (tid == 0) out[b] = (float)((cnt < KEEP) ? cnt : KEEP);
}

// ---------------------------------------------------------------- launch
extern "C" void kernel_launch(void* const* d_in, const int* in_sizes, int n_in,
                              void* d_out, int out_size, void* d_ws, size_t ws_size,
                              hipStream_t stream) {
    const float* cls0 = (const float*)d_in[0];
    const float* bb0  = (const float*)d_in[1];
    const float* obj0 = (const float*)d_in[2];
    const float* cls1 = (const float*)d_in[3];
    const float* bb1  = (const float*)d_in[4];
    const float* obj1 = (const float*)d_in[5];
    const float* cls2 = (const float*)d_in[6];
    const float* bb2  = (const float*)d_in[7];
    const float* obj2 = (const float*)d_in[8];
    float* out = (float*)d_out;

    char* ws = (char*)d_ws;
    float*  keptScore = (float*)(ws);                  //   256,000 B
    float4* keptBox   = (float4*)(ws + 256000);        // 1,024,000 B

    select_nms<<<NB * NCLS, TBS, 0, stream>>>(cls0, bb0, obj0, cls1, bb1, obj1,
                                              cls2, bb2, obj2, keptScore, keptBox);
    topk_out<<<NB, TBT, 0, stream>>>(keptScore, keptBox, out);
}

// Round 13
// 179.539 us; speedup vs baseline: 1.9023x; 1.0201x over previous
//
#include <hip/hip_runtime.h>
#include <math.h>
#include <stdint.h>

#define NCLS   80
#define NPTS   8400
#define KEEP   100
#define PRETOPK 5000
#define NB     8
#define THRBITS 0x3C23D70Au   // bits of 0.01f (scores positive floats -> int-ordered)

#define TBS    1024           // select block size
#define CAPF   512            // candidate cap
#define NEEDF  192u           // selection target
#define MTX    256            // suppression-matrix size
#define NW4    2100           // NPTS / 4 (uint4 words)

#define TBT    1024           // topk block size
#define NREGT  8              // 8000/1024
#define CAPT   512

__device__ __forceinline__ float sigmoidf_(float x) { return 1.0f / (1.0f + expf(-x)); }

__device__ __forceinline__ float4 decode_one(int n, int b,
        const float* bb0, const float* bb1, const float* bb2) {
    const float* bb; int base, HW, x, y; float s;
    if (n < 6400)      { bb = bb0; base = n;        HW = 6400; s = 8.f;  y = base / 80; x = base - y * 80; }
    else if (n < 8000) { bb = bb1; base = n - 6400; HW = 1600; s = 16.f; y = base / 40; x = base - y * 40; }
    else               { bb = bb2; base = n - 8000; HW = 400;  s = 32.f; y = base / 20; x = base - y * 20; }
    const float* p = bb + (size_t)b * 4 * HW + base;
    float v0 = p[0], v1 = p[HW], v2 = p[2 * HW], v3 = p[3 * HW];
    float cx = v0 * s + x * s, cy = v1 * s + y * s;
    float w = expf(v2) * s, h = expf(v3) * s;
    return make_float4(cx - 0.5f * w, cy - 0.5f * h, cx + 0.5f * w, cy + 0.5f * h);
}

__device__ __forceinline__ bool iou_gt(float4 a, float4 c) {
    float tlx = fmaxf(a.x, c.x), tly = fmaxf(a.y, c.y);
    float brx = fminf(a.z, c.z), bry = fminf(a.w, c.w);
    float w = fmaxf(brx - tlx, 0.f), h = fmaxf(bry - tly, 0.f);
    float inter = w * h;
    float a1 = (a.z - a.x) * (a.w - a.y);
    float a2 = (c.z - c.x) * (c.w - c.y);
    return inter / (a1 + a2 - inter + 1e-6f) > 0.65f;
}

// ---------------------------------------------------------------- sigmoid(obj) precompute (once per image)
__global__ __launch_bounds__(1024)
void sig_obj(const float* __restrict__ o0, const float* __restrict__ o1, const float* __restrict__ o2,
             float* __restrict__ so) {
    int t = blockIdx.x * 1024 + threadIdx.x;
    if (t >= NB * NPTS) return;
    int b = t / NPTS, n = t - b * NPTS;
    float v;
    if (n < 6400)      v = o0[(size_t)b * 6400 + n];
    else if (n < 8000) v = o1[(size_t)b * 1600 + (n - 6400)];
    else               v = o2[(size_t)b * 400 + (n - 8000)];
    so[t] = 1.0f / (1.0f + expf(-v));
}

// ================================================================ fused per-(b,c) select + sort + NMS
__global__ __launch_bounds__(TBS, 8)
void select_nms(const float* __restrict__ cls0, const float* __restrict__ bb0,
                const float* __restrict__ cls1, const float* __restrict__ bb1,
                const float* __restrict__ cls2, const float* __restrict__ bb2,
                const float* __restrict__ sigObj,
                float* __restrict__ keptScore, float4* __restrict__ keptBox) {
    __shared__ __align__(16) uint32_t sKey[NPTS];                // 33.6 KB
    __shared__ uint32_t sHist[1024];                             // 4 KB
    __shared__ __align__(16) unsigned long long cPack[CAPF + 16];// 4.2 KB
    __shared__ uint32_t sKeyS[CAPF];                             // 2 KB
    __shared__ uint16_t sIdxS[CAPF];                             // 1 KB
    __shared__ float4   bBoxS[CAPF];                             // 8 KB
    __shared__ __align__(16) unsigned long long colM[MTX][4];    // 8 KB
    __shared__ uint32_t shr[4];
    __shared__ unsigned long long sh64;

    int bc = blockIdx.x;
    int b = bc & 7;                  // XCD-locality: image b -> XCD b
    int c = bc >> 3;
    int tid = threadIdx.x, lane = tid & 63;

    // ---- phase 1: keygen (float4 loads) -> LDS, fused with level-0 histogram
    sHist[tid] = 0;
    __syncthreads();
    uint4* sKey4 = (uint4*)sKey;
    #pragma unroll
    for (int i = 0; i < 3; ++i) {
        int w = tid + i * TBS;
        if (w < NW4) {
            int n = w << 2;
            const float* cp;
            if (w < 1600)      cp = cls0 + ((size_t)b * NCLS + c) * 6400 + n;
            else if (w < 2000) cp = cls1 + ((size_t)b * NCLS + c) * 1600 + (n - 6400);
            else               cp = cls2 + ((size_t)b * NCLS + c) * 400 + (n - 8000);
            float4 cv = *(const float4*)cp;
            float4 so = *(const float4*)(sigObj + (size_t)b * NPTS + n);
            uint32_t k0 = __float_as_uint(sigmoidf_(cv.x) * so.x);
            uint32_t k1 = __float_as_uint(sigmoidf_(cv.y) * so.y);
            uint32_t k2 = __float_as_uint(sigmoidf_(cv.z) * so.z);
            uint32_t k3 = __float_as_uint(sigmoidf_(cv.w) * so.w);
            sKey4[w] = make_uint4(k0, k1, k2, k3);
            if (k0 > THRBITS) atomicAdd(&sHist[k0 >> 22], 1u);
            if (k1 > THRBITS) atomicAdd(&sHist[k1 >> 22], 1u);
            if (k2 > THRBITS) atomicAdd(&sHist[k2 >> 22], 1u);
            if (k3 > THRBITS) atomicAdd(&sHist[k3 >> 22], 1u);
        }
    }
    __syncthreads();

    // ---- phase 2: exact radix threshold selection (levels 10/10/10/2 bits), array-free scans
    uint32_t prefix = 0, carry = 0, Tsel = 0;
    const uint4* k4 = (const uint4*)sKey;
    for (int level = 0;; ++level) {
        int shift = (level == 0) ? 22 : (level == 1) ? 12 : (level == 2) ? 2 : 0;
        bool nb4 = (level == 3);
        if (tid < 64) {
            if (!nb4) {
                const uint4* hv = (const uint4*)sHist;
                uint4 q0 = hv[lane * 4], q1 = hv[lane * 4 + 1], q2 = hv[lane * 4 + 2], q3 = hv[lane * 4 + 3];
                uint32_t csum = q0.x + q0.y + q0.z + q0.w + q1.x + q1.y + q1.z + q1.w
                              + q2.x + q2.y + q2.z + q2.w + q3.x + q3.y + q3.z + q3.w;
                uint32_t suf = csum;
                #pragma unroll
                for (int d = 1; d < 64; d <<= 1) {
                    uint32_t t = (uint32_t)__shfl_down((int)suf, d);
                    if (lane + d < 64) suf += t;
                }
                unsigned long long m = __ballot(carry + suf >= NEEDF);
                if (!m) { if (lane == 0) { shr[1] = 0u; shr[0] = 0u; } }
                else {
                    int l1 = 63 - __clzll(m);
                    uint32_t carry2 = carry + (uint32_t)__shfl((int)suf, l1) - (uint32_t)__shfl((int)csum, l1);
                    // stage 2: 16-lane shfl suffix scan over the crossing chunk (no local array)
                    uint32_t c2 = (lane < 16) ? sHist[l1 * 16 + lane] : 0u;
                    uint32_t suf2 = c2;
                    #pragma unroll
                    for (int d = 1; d < 16; d <<= 1) {
                        uint32_t t = (uint32_t)__shfl_down((int)suf2, d);
                        if (lane + d < 16) suf2 += t;
                    }
                    unsigned long long m2 = __ballot(lane < 16 && (carry2 + suf2 >= NEEDF));
                    int t2 = m2 ? (63 - __clzll(m2)) : 0;
                    uint32_t suf2L = (uint32_t)__shfl((int)suf2, t2);
                    uint32_t c2L   = (uint32_t)__shfl((int)c2, t2);
                    int bin = l1 * 16 + t2;
                    uint32_t cAbove = carry2 + suf2L - c2L;
                    uint32_t cntIncl = cAbove + c2L;
                    if (lane == 0) {
                        if (cntIncl <= CAPF) { shr[1] = 0u; shr[0] = prefix | ((uint32_t)bin << shift); }
                        else { shr[1] = 1u; shr[2] = prefix | ((uint32_t)bin << shift); shr[3] = cAbove; }
                    }
                }
            } else {
                uint32_t c2 = (lane < 4) ? sHist[lane] : 0u;
                uint32_t suf2 = c2;
                #pragma unroll
                for (int d = 1; d < 4; d <<= 1) {
                    uint32_t t = (uint32_t)__shfl_down((int)suf2, d);
                    if (lane + d < 4) suf2 += t;
                }
                unsigned long long m2 = __ballot(lane < 4 && (carry + suf2 >= NEEDF));
                int t2 = m2 ? (63 - __clzll(m2)) : 0;
                uint32_t suf2L = (uint32_t)__shfl((int)suf2, t2);
                uint32_t c2L   = (uint32_t)__shfl((int)c2, t2);
                uint32_t cAbove = carry + suf2L - c2L;
                uint32_t cntIncl = cAbove + c2L;
                if (lane == 0) {
                    shr[1] = 0u;
                    if (cntIncl <= CAPF) shr[0] = prefix | (uint32_t)t2;
                    else shr[0] = (prefix | (uint32_t)t2) + 1u;   // exclude exact tie-key; continuation recovers
                }
            }
        }
        __syncthreads();
        if (shr[1] == 0u) { Tsel = shr[0]; break; }
        prefix = shr[2]; carry = shr[3];
        // build next level's histogram from LDS keys
        int nl = level + 1;
        if (nl == 3) { if (tid < 4) sHist[tid] = 0; } else sHist[tid] = 0;
        __syncthreads();
        #pragma unroll
        for (int i = 0; i < 3; ++i) {
            int w = tid + i * 1024;
            if (w < NW4) {
                uint4 q = k4[w];
                uint32_t k;
                k = q.x;
                if (k > THRBITS) {
                    if (nl == 1) { if ((k >> 22) == (prefix >> 22)) atomicAdd(&sHist[(k >> 12) & 1023u], 1u); }
                    else if (nl == 2) { if ((k >> 12) == (prefix >> 12)) atomicAdd(&sHist[(k >> 2) & 1023u], 1u); }
                    else { if ((k >> 2) == (prefix >> 2)) atomicAdd(&sHist[k & 3u], 1u); }
                }
                k = q.y;
                if (k > THRBITS) {
                    if (nl == 1) { if ((k >> 22) == (prefix >> 22)) atomicAdd(&sHist[(k >> 12) & 1023u], 1u); }
                    else if (nl == 2) { if ((k >> 12) == (prefix >> 12)) atomicAdd(&sHist[(k >> 2) & 1023u], 1u); }
                    else { if ((k >> 2) == (prefix >> 2)) atomicAdd(&sHist[k & 3u], 1u); }
                }
                k = q.z;
                if (k > THRBITS) {
                    if (nl == 1) { if ((k >> 22) == (prefix >> 22)) atomicAdd(&sHist[(k >> 12) & 1023u], 1u); }
                    else if (nl == 2) { if ((k >> 12) == (prefix >> 12)) atomicAdd(&sHist[(k >> 2) & 1023u], 1u); }
                    else { if ((k >> 2) == (prefix >> 2)) atomicAdd(&sHist[k & 3u], 1u); }
                }
                k = q.w;
                if (k > THRBITS) {
                    if (nl == 1) { if ((k >> 22) == (prefix >> 22)) atomicAdd(&sHist[(k >> 12) & 1023u], 1u); }
                    else if (nl == 2) { if ((k >> 12) == (prefix >> 12)) atomicAdd(&sHist[(k >> 2) & 1023u], 1u); }
                    else { if ((k >> 2) == (prefix >> 2)) atomicAdd(&sHist[k & 3u], 1u); }
                }
            }
        }
        __syncthreads();
    }
    __syncthreads();
    if (tid == 0) shr[3] = 0u;
    __syncthreads();

    // ---- phase 3: compact from LDS keys (packed u64: key<<32 | (0xFFFF - n))
    #pragma unroll
    for (int i = 0; i < 3; ++i) {
        int w = tid + i * 1024;
        if (w < NW4) {
            uint4 q = k4[w];
            uint32_t k; int n = w << 2;
            k = q.x;
            if (k > THRBITS && k >= Tsel) {
                uint32_t s = atomicAdd(&shr[3], 1u);
                if (s < CAPF) cPack[s] = ((unsigned long long)k << 32) | (uint32_t)(0xFFFFu - n);
            }
            k = q.y;
            if (k > THRBITS && k >= Tsel) {
                uint32_t s = atomicAdd(&shr[3], 1u);
                if (s < CAPF) cPack[s] = ((unsigned long long)k << 32) | (uint32_t)(0xFFFFu - (n + 1));
            }
            k = q.z;
            if (k > THRBITS && k >= Tsel) {
                uint32_t s = atomicAdd(&shr[3], 1u);
                if (s < CAPF) cPack[s] = ((unsigned long long)k << 32) | (uint32_t)(0xFFFFu - (n + 2));
            }
            k = q.w;
            if (k > THRBITS && k >= Tsel) {
                uint32_t s = atomicAdd(&shr[3], 1u);
                if (s < CAPF) cPack[s] = ((unsigned long long)k << 32) | (uint32_t)(0xFFFFu - (n + 3));
            }
        }
    }
    __syncthreads();
    int cnt = (int)shr[3]; if (cnt > CAPF) cnt = CAPF;
    if (tid < 16) cPack[cnt + tid] = 0ull;
    __syncthreads();

    // ---- phase 4: rank-sort, participating waves only, 16 cands/iter (b128 reads)
    if (tid < ((cnt + 63) & ~63)) {
        bool h0 = tid < cnt;
        unsigned long long my = h0 ? cPack[tid] : 0ull;
        int r0 = 0;
        const ulonglong2* cp2 = (const ulonglong2*)cPack;
        int nb16 = (cnt + 15) >> 4;
        for (int jb = 0; jb < nb16; ++jb) {
            ulonglong2 p0 = cp2[jb * 8 + 0], p1 = cp2[jb * 8 + 1], p2 = cp2[jb * 8 + 2], p3 = cp2[jb * 8 + 3];
            ulonglong2 p4 = cp2[jb * 8 + 4], p5 = cp2[jb * 8 + 5], p6 = cp2[jb * 8 + 6], p7 = cp2[jb * 8 + 7];
            r0 += (p0.x > my) + (p0.y > my) + (p1.x > my) + (p1.y > my)
                + (p2.x > my) + (p2.y > my) + (p3.x > my) + (p3.y > my)
                + (p4.x > my) + (p4.y > my) + (p5.x > my) + (p5.y > my)
                + (p6.x > my) + (p6.y > my) + (p7.x > my) + (p7.y > my);
        }
        if (h0) {
            sKeyS[r0] = (uint32_t)(my >> 32);
            sIdxS[r0] = (uint16_t)(0xFFFFu - (uint32_t)(my & 0xFFFFu));
        }
    }
    __syncthreads();

    // ---- phase 5: gather + inline-decode candidate boxes
    if (tid < cnt) bBoxS[tid] = decode_one(sIdxS[tid], b, bb0, bb1, bb2);
    __syncthreads();

    // ---- phase 6: suppression bitmatrix (IoU symmetric)
    int lim = (cnt < MTX) ? cnt : MTX;
    {
        int cand = tid & 255, rb = tid >> 8;
        unsigned long long m = 0ull;
        if (cand < lim) {
            float4 bcx = bBoxS[cand];
            int j0 = rb << 6;
            #pragma unroll 8
            for (int jj = 0; jj < 64; ++jj)
                if (iou_gt(bBoxS[j0 + jj], bcx)) m |= 1ull << jj;
        }
        colM[cand][rb] = m;
    }
    __syncthreads();

    // ---- phase 7: serial walk on wave 0 — ffs-jump, rows from LDS (broadcast b128)
    float4 kb0 = make_float4(0.f, 0.f, 0.f, 0.f), kb1 = kb0;
    float ks0 = -1.0f, ks1 = -1.0f;
    int K = 0;
    if (tid < 64) {
        unsigned long long U0, U1, U2, U3;
        U0 = (lim >= 64) ? ~0ull : ((lim > 0) ? ((1ull << lim) - 1) : 0ull);
        U1 = (lim >= 128) ? ~0ull : ((lim > 64) ? ((1ull << (lim - 64)) - 1) : 0ull);
        U2 = (lim >= 192) ? ~0ull : ((lim > 128) ? ((1ull << (lim - 128)) - 1) : 0ull);
        U3 = (lim >= 256) ? ~0ull : ((lim > 192) ? ((1ull << (lim - 192)) - 1) : 0ull);
        int kIA = -1, kIB = -1;
        while (K < KEEP) {
            int i;
            if (U0) i = (int)__ffsll(U0) - 1;
            else if (U1) i = 64 + (int)__ffsll(U1) - 1;
            else if (U2) i = 128 + (int)__ffsll(U2) - 1;
            else if (U3) i = 192 + (int)__ffsll(U3) - 1;
            else break;
            ulonglong2 r01 = *(const ulonglong2*)&colM[i][0];   // broadcast
            ulonglong2 r23 = *(const ulonglong2*)&colM[i][2];
            if (i < 64)       U0 &= ~(1ull << i);
            else if (i < 128) U1 &= ~(1ull << (i - 64));
            else if (i < 192) U2 &= ~(1ull << (i - 128));
            else              U3 &= ~(1ull << (i - 192));
            U0 &= ~r01.x; U1 &= ~r01.y; U2 &= ~r23.x; U3 &= ~r23.y;
            if (K < 64) { if (lane == K) kIA = i; }
            else        { if (lane == K - 64) kIB = i; }
            K++;
        }
        if (kIA >= 0) { kb0 = bBoxS[kIA]; ks0 = __uint_as_float(sKeyS[kIA]); }
        if (kIB >= 0) { kb1 = bBoxS[kIB]; ks1 = __uint_as_float(sKeyS[kIB]); }
        // mid-walk beyond matrix (cnt > MTX; rare)
        for (int i = lim; i < cnt && K < KEEP; ++i) {
            float4 bx = bBoxS[i];
            bool sup = false;
            if (lane < K)      sup = iou_gt(bx, kb0);
            if (64 + lane < K) sup = sup || iou_gt(bx, kb1);
            if (!__any(sup ? 1 : 0)) {
                float sc = __uint_as_float(sKeyS[i]);
                if (K < 64) { if (lane == K)      { kb0 = bx; ks0 = sc; } }
                else        { if (lane == K - 64) { kb1 = bx; ks1 = sc; } }
                K++;
            }
        }
        if (lane == 0) {
            shr[0] = (uint32_t)K;
            shr[1] = (uint32_t)cnt;
            shr[2] = (cnt > 0) ? sKeyS[cnt - 1] : 0xFFFFFFFFu;
            shr[3] = (cnt > 0) ? (uint32_t)sIdxS[cnt - 1] : 0xFFFFFFFFu;
        }
    }
    __syncthreads();
    int Kall = (int)shr[0]; int e = (int)shr[1];
    uint32_t cK = shr[2], cI = shr[3];

    // ---- phase 8: exact continuation via block argmax over LDS keys (rare)
    if (Kall < KEEP && e < PRETOPK) {
        for (;;) {
            if (tid == 0) sh64 = 0ull;
            __syncthreads();
            unsigned long long best = 0ull;
            for (int i = 0; i < 9; ++i) {
                int n = tid + i * TBS;
                if (n < NPTS) {
                    uint32_t k = sKey[n];
                    if (k > THRBITS && (k < cK || (k == cK && (uint32_t)n > cI))) {
                        unsigned long long v = ((unsigned long long)k << 32) | (unsigned long long)(NPTS - 1 - n);
                        if (v > best) best = v;
                    }
                }
            }
            if (best) atomicMax(&sh64, best);
            __syncthreads();
            unsigned long long bv = sh64;
            if (bv == 0ull) break;
            uint32_t k = (uint32_t)(bv >> 32);
            int n = NPTS - 1 - (int)(bv & 0xFFFFFFFFull);
            if (tid < 64) {
                float4 bx = decode_one(n, b, bb0, bb1, bb2);
                bool sup = false;
                if (lane < K)      sup = iou_gt(bx, kb0);
                if (64 + lane < K) sup = sup || iou_gt(bx, kb1);
                if (!__any(sup ? 1 : 0)) {
                    float sc = __uint_as_float(k);
                    if (K < 64) { if (lane == K)      { kb0 = bx; ks0 = sc; } }
                    else        { if (lane == K - 64) { kb1 = bx; ks1 = sc; } }
                    K++;
                }
                if (lane == 0) shr[0] = (uint32_t)K;
            }
            __syncthreads();
            Kall = (int)shr[0];
            e++; cK = k; cI = (uint32_t)n;
            if (Kall >= KEEP || e >= PRETOPK) break;
        }
    }

    // ---- write per-class results
    if (tid < 64) {
        int off = (b * NCLS + c) * KEEP;
        float4 z = make_float4(0.f, 0.f, 0.f, 0.f);
        keptScore[off + lane] = (lane < K) ? ks0 : -1.0f;
        keptBox[off + lane]   = (lane < K) ? kb0 : z;
        if (64 + lane < KEEP) {
            keptScore[off + 64 + lane] = (64 + lane < K) ? ks1 : -1.0f;
            keptBox[off + 64 + lane]   = (64 + lane < K) ? kb1 : z;
        }
    }
}

// ---------------------------------------------------------------- topk (unchanged)
__device__ void scan_cross_fast(const uint32_t* hist, int nb, uint32_t need, uint32_t cap,
                                uint32_t carry, uint32_t prefix, int shift, int level,
                                uint32_t* shr, int lane) {
    uint32_t csum;
    if (nb == 4096) {
        uint32_t s = 0;
        int cb = lane << 6;
        #pragma unroll 8
        for (int i = 0; i < 64; ++i) s += hist[cb + i];
        csum = s;
    } else {
        csum = hist[lane];
    }
    uint32_t suf = csum;
    #pragma unroll
    for (int d = 1; d < 64; d <<= 1) {
        uint32_t t = (uint32_t)__shfl_down((int)suf, d);
        if (lane + d < 64) suf += t;
    }
    unsigned long long m = __ballot(carry + suf >= need);
    if (!m) { if (lane == 0) { shr[1] = 0u; shr[0] = 0u; } return; }
    int l1 = 63 - __clzll(m);
    uint32_t sufL1 = (uint32_t)__shfl((int)suf, l1);
    uint32_t csumL1 = (uint32_t)__shfl((int)csum, l1);
    uint32_t carry2 = carry + sufL1 - csumL1;
    int foundBin; uint32_t cAbove, bCnt;
    if (nb == 4096) {
        int cb = l1 << 6;
        uint32_t c2 = hist[cb + lane];
        uint32_t suf2 = c2;
        #pragma unroll
        for (int d = 1; d < 64; d <<= 1) {
            uint32_t t = (uint32_t)__shfl_down((int)suf2, d);
            if (lane + d < 64) suf2 += t;
        }
        unsigned long long m2 = __ballot(carry2 + suf2 >= need);
        int l2 = 63 - __clzll(m2);
        foundBin = cb + l2;
        uint32_t suf2L = (uint32_t)__shfl((int)suf2, l2);
        uint32_t c2L = (uint32_t)__shfl((int)c2, l2);
        cAbove = carry2 + suf2L - c2L;
        bCnt = c2L;
    } else {
        foundBin = l1; cAbove = carry2; bCnt = csumL1;
    }
    if (lane == 0) {
        uint32_t cntIncl = cAbove + bCnt;
        if (cntIncl <= cap) { shr[1] = 0u; shr[0] = prefix | ((uint32_t)foundBin << shift); }
        else if (level == 2) { shr[1] = 0u; shr[0] = (prefix | (uint32_t)foundBin) + 1u; }
        else { shr[1] = 1u; shr[2] = prefix | ((uint32_t)foundBin << shift); shr[3] = cAbove; }
    }
}

__global__ __launch_bounds__(TBT)
void topk_out(const float* __restrict__ keptScore, const float4* __restrict__ keptBox,
              float* __restrict__ out) {
    __shared__ uint32_t sHist[4096];
    __shared__ __align__(16) unsigned long long cPackT[CAPT + 16];
    __shared__ uint32_t sKeyS[CAPT];
    __shared__ uint16_t sIdxS[CAPT];
    __shared__ uint32_t shr[4];
    int b = blockIdx.x, tid = threadIdx.x, lane = tid & 63;
    const int TOT = NCLS * KEEP;

    uint32_t rKey[NREGT];
    #pragma unroll
    for (int i = 0; i < NREGT; ++i) {
        int n = tid + i * TBT;
        uint32_t key = 0u;
        if (n < TOT) {
            float s = keptScore[b * TOT + n];
            key = (s > 0.f) ? __float_as_uint(s) : 0u;
        }
        rKey[i] = key;
    }

    uint32_t prefix = 0, carry = 0, Tsel = 0;
    for (int level = 0;; ++level) {
        int shift = (level == 0) ? 18 : (level == 1 ? 6 : 0);
        int nb = (level == 2) ? 64 : 4096;
        __syncthreads();
        for (int i = tid; i < nb; i += TBT) sHist[i] = 0;
        __syncthreads();
        #pragma unroll
        for (int i = 0; i < NREGT; ++i) {
            uint32_t k = rKey[i];
            if (k > 0u) {
                if (level == 0) atomicAdd(&sHist[k >> 18], 1u);
                else if (level == 1) { if ((k >> 18) == (prefix >> 18)) atomicAdd(&sHist[(k >> 6) & 0xFFFu], 1u); }
                else { if ((k >> 6) == (prefix >> 6)) atomicAdd(&sHist[k & 0x3Fu], 1u); }
            }
        }
        __syncthreads();
        if (tid < 64) scan_cross_fast(sHist, nb, (uint32_t)KEEP, CAPT, carry, prefix, shift, level, shr, lane);
        __syncthreads();
        if (shr[1] == 0u) { Tsel = shr[0]; break; }
        prefix = shr[2]; carry = shr[3];
    }
    __syncthreads();
    if (tid == 0) shr[3] = 0u;
    __syncthreads();
    #pragma unroll
    for (int i = 0; i < NREGT; ++i) {
        uint32_t k = rKey[i];
        if (k > 0u && k >= Tsel) {
            uint32_t s = atomicAdd(&shr[3], 1u);
            if (s < CAPT) cPackT[s] = ((unsigned long long)k << 32) | (uint32_t)(0xFFFFu - (tid + i * TBT));
        }
    }
    __syncthreads();
    int cnt = (int)shr[3]; if (cnt > CAPT) cnt = CAPT;
    if (tid < 16) cPackT[cnt + tid] = 0ull;
    __syncthreads();

    if (tid < ((cnt + 63) & ~63)) {
        bool h0 = tid < cnt;
        unsigned long long my = h0 ? cPackT[tid] : 0ull;
        int r0 = 0;
        const ulonglong2* cp2 = (const ulonglong2*)cPackT;
        int nb16 = (cnt + 15) >> 4;
        for (int jb = 0; jb < nb16; ++jb) {
            ulonglong2 p0 = cp2[jb * 8 + 0], p1 = cp2[jb * 8 + 1], p2 = cp2[jb * 8 + 2], p3 = cp2[jb * 8 + 3];
            ulonglong2 p4 = cp2[jb * 8 + 4], p5 = cp2[jb * 8 + 5], p6 = cp2[jb * 8 + 6], p7 = cp2[jb * 8 + 7];
            r0 += (p0.x > my) + (p0.y > my) + (p1.x > my) + (p1.y > my)
                + (p2.x > my) + (p2.y > my) + (p3.x > my) + (p3.y > my)
                + (p4.x > my) + (p4.y > my) + (p5.x > my) + (p5.y > my)
                + (p6.x > my) + (p6.y > my) + (p7.x > my) + (p7.y > my);
        }
        if (h0) {
            sKeyS[r0] = (uint32_t)(my >> 32);
            sIdxS[r0] = (uint16_t)(0xFFFFu - (uint32_t)(my & 0xFFFFu));
        }
    }
    __syncthreads();

    if (tid < KEEP) {
        bool valid = tid < cnt;
        int fi = valid ? (int)sIdxS[tid] : 0;
        float sc = valid ? __uint_as_float(sKeyS[tid]) : 0.f;
        float4 bx = valid ? keptBox[b * TOT + fi] : make_float4(0.f, 0.f, 0.f, 0.f);
        float cls = valid ? (float)(fi / KEEP) : -1.0f;
        float* boxOut = out + NB + (b * KEEP + tid) * 4;
        boxOut[0] = bx.x; boxOut[1] = bx.y; boxOut[2] = bx.z; boxOut[3] = bx.w;
        out[NB + NB * KEEP * 4 + b * KEEP + tid] = sc;
        out[NB + NB * KEEP * 4 + NB * KEEP + b * KEEP + tid] = cls;
    }
    if (tid == 0) out[b] = (float)((cnt < KEEP) ? cnt : KEEP);
}

// ---------------------------------------------------------------- launch
extern "C" void kernel_launch(void* const* d_in, const int* in_sizes, int n_in,
                              void* d_out, int out_size, void* d_ws, size_t ws_size,
                              hipStream_t stream) {
    const float* cls0 = (const float*)d_in[0];
    const float* bb0  = (const float*)d_in[1];
    const float* obj0 = (const float*)d_in[2];
    const float* cls1 = (const float*)d_in[3];
    const float* bb1  = (const float*)d_in[4];
    const float* obj1 = (const float*)d_in[5];
    const float* cls2 = (const float*)d_in[6];
    const float* bb2  = (const float*)d_in[7];
    const float* obj2 = (const float*)d_in[8];
    float* out = (float*)d_out;

    char* ws = (char*)d_ws;
    float*  keptScore = (float*)(ws);                  //   256,000 B
    float4* keptBox   = (float4*)(ws + 256000);        // 1,024,000 B
    float*  sigObj    = (float*)(ws + 1280000);        //   268,800 B

    sig_obj<<<(NB * NPTS + 1023) / 1024, 1024, 0, stream>>>(obj0, obj1, obj2, sigObj);
    select_nms<<<NB * NCLS, TBS, 0, stream>>>(cls0, bb0, cls1, bb1, cls2, bb2,
                                              sigObj, keptScore, keptBox);
    topk_out<<<NB, TBT, 0, stream>>>(keptScore, keptBox, out);
}